// Round 4
// baseline (272.157 us; speedup 1.0000x reference)
//
#include <hip/hip_runtime.h>

// Problem constants: B=8, C=128, L=2048, H=4, D=32
#define Bsz 8
#define Cdim 128
#define Lseq 2048
#define NH 4
#define HD 32
#define BH 32
// scale folded with log2(e): scores feed v_exp_f32 (exp2) directly
#define QSCALE (0.17677669529663687f * 1.4426950408889634f)

typedef __bf16 bf16x8 __attribute__((ext_vector_type(8)));
typedef float f32x4 __attribute__((ext_vector_type(4)));

__device__ __forceinline__ float fexp2(float x) {
#if __has_builtin(__builtin_amdgcn_exp2f)
    return __builtin_amdgcn_exp2f(x);
#else
    return __expf(x * 0.6931471805599453f);
#endif
}

__device__ __forceinline__ unsigned short f2bf(float f) {
    unsigned u = __builtin_bit_cast(unsigned, f);
    u += 0x7FFFu + ((u >> 16) & 1u);     // round-to-nearest-even
    return (unsigned short)(u >> 16);
}

__device__ __forceinline__ unsigned pack_bf16(float a, float b) {
    return (unsigned)f2bf(a) | ((unsigned)f2bf(b) << 16);
}

// ---------------------------------------------------------------------------
// Kernel 1: QKV projection (fp32 GEMM, bf16 out). 48 outputs/thread: x is
// re-fetched x8 instead of x24 (HBM 192->64 MB).
//   Q,K -> [BH][L][32] (d contiguous), V -> [BH][32][L]. log2e*scale in Q.
// ---------------------------------------------------------------------------
__global__ __launch_bounds__(256) void qkv_kernel(const float* __restrict__ x,
        const float* __restrict__ w, const float* __restrict__ bias,
        unsigned short* __restrict__ qh, unsigned short* __restrict__ kh,
        unsigned short* __restrict__ vh) {
    int bid = blockIdx.x;
    int og = bid & 7;            // 8 o-groups of 48
    int lt = (bid >> 3) & 7;     // 8 l-tiles of 256
    int b  = bid >> 6;
    int l  = lt * 256 + threadIdx.x;
    int o0 = og * 48;
    float acc[48];
    #pragma unroll
    for (int i = 0; i < 48; i++) acc[i] = bias[o0 + i];
    const float* xb = x + (size_t)b * Cdim * Lseq + l;
    #pragma unroll 4
    for (int c = 0; c < Cdim; c++) {
        float xv = xb[(size_t)c * Lseq];
        #pragma unroll
        for (int i = 0; i < 48; i++) acc[i] += w[(o0 + i) * Cdim + c] * xv;
    }
    // store in 3 chunks of 16 outputs (16-aligned => never crosses a d-half)
    #pragma unroll
    for (int cc = 0; cc < 3; cc++) {
        int oc = o0 + cc * 16;
        const float* a = acc + cc * 16;
        int h  = (oc >> 5) & 3;
        int d0 = oc & 31;          // 0 or 16
        int bh = b * NH + h;
        if (oc < Cdim) {           // Q (scaled by 1/sqrt(D)*log2e)
            unsigned us[8];
            #pragma unroll
            for (int i = 0; i < 8; i++)
                us[i] = pack_bf16(a[2*i] * QSCALE, a[2*i+1] * QSCALE);
            unsigned short* base = qh + ((size_t)bh * Lseq + l) * HD + d0;
            ((uint4*)base)[0]       = make_uint4(us[0], us[1], us[2], us[3]);
            ((uint4*)(base + 8))[0] = make_uint4(us[4], us[5], us[6], us[7]);
        } else if (oc < 2 * Cdim) { // K
            unsigned us[8];
            #pragma unroll
            for (int i = 0; i < 8; i++)
                us[i] = pack_bf16(a[2*i], a[2*i+1]);
            unsigned short* base = kh + ((size_t)bh * Lseq + l) * HD + d0;
            ((uint4*)base)[0]       = make_uint4(us[0], us[1], us[2], us[3]);
            ((uint4*)(base + 8))[0] = make_uint4(us[4], us[5], us[6], us[7]);
        } else {                    // V transposed [BH][32][L]
            #pragma unroll
            for (int i = 0; i < 16; i++)
                vh[((size_t)bh * HD + d0 + i) * Lseq + l] = f2bf(a[i]);
        }
    }
}

// ---------------------------------------------------------------------------
// Kernel 2: MFMA flash attention, barrier-free.
//   S' = K*Q^T  (A=K,B=Q): C-layout => lane(q,m): query=m (lane), key=4q+r (reg)
//   -> exp2 -> pack 4 key-contiguous bf16 -> 1 ds_write_b64 per 16-key tile
//   -> PV as O^T = V*P^T (A=V,B=P): B-frag = contiguous ds_read_b128.
//   O^T C-layout: query in lane => direct coalesced store, no transpose stage.
// plds is wave-private; per-wave LDS FIFO + s_waitcnt lgkmcnt(0), NO barriers.
// Row stride 72 ushort (144B): 16B-aligned rows, only free 2-way conflicts.
// ---------------------------------------------------------------------------
__global__ __launch_bounds__(256) void attn_kernel(
        const unsigned short* __restrict__ qh, const unsigned short* __restrict__ kh,
        const unsigned short* __restrict__ vh, unsigned short* __restrict__ attnb) {
    __shared__ unsigned short plds[4][16][72];   // [wave][query][key 0..63]

    int bid = blockIdx.x;
    int xcd  = bid & 7;                 // keep each bh's K/V on one XCD L2
    int rest = bid >> 3;
    int qt = rest & 31;                 // 32 q-tiles of 64 rows
    int bh = xcd + 8 * (rest >> 5);

    int lane = threadIdx.x & 63;
    int wv   = threadIdx.x >> 6;
    int m16  = lane & 15;
    int quad = lane >> 4;
    int l0 = qt * 64 + wv * 16;

    // Q B-frag: B[k=d=quad*8+j][n=query=lane&15]
    bf16x8 qf = *(const bf16x8*)(qh + ((size_t)bh * Lseq + l0 + m16) * HD + quad * 8);

    const unsigned short* kb  = kh + (size_t)bh * Lseq * HD + (size_t)m16 * HD + quad * 8;
    const unsigned short* vb0 = vh + (size_t)bh * HD * Lseq + (size_t)m16 * Lseq + quad * 8;
    const unsigned short* vb1 = vb0 + 16 * Lseq;

    f32x4 oacc0 = {0.f, 0.f, 0.f, 0.f};   // O^T[d=0..15][query]
    f32x4 oacc1 = {0.f, 0.f, 0.f, 0.f};   // O^T[d=16..31][query]
    f32x4 zero  = {0.f, 0.f, 0.f, 0.f};
    float lp = 0.f;
    unsigned short* prow = &plds[wv][m16][0];

    for (int it = 0; it < Lseq / 64; it++) {
        int k0 = it * 64;
        // K A-frags: A[m=key=lane&15][k=d=quad*8+j], K stored [key][d]
        bf16x8 kf0 = *(const bf16x8*)(kb + (size_t)(k0     ) * HD);
        bf16x8 kf1 = *(const bf16x8*)(kb + (size_t)(k0 + 16) * HD);
        bf16x8 kf2 = *(const bf16x8*)(kb + (size_t)(k0 + 32) * HD);
        bf16x8 kf3 = *(const bf16x8*)(kb + (size_t)(k0 + 48) * HD);
        // V A-frags: A[m=d=lane&15][k=key=quad*8+j], V stored [d][key]
        bf16x8 vf00 = *(const bf16x8*)(vb0 + k0);        // d 0-15,  keys k0..k0+31
        bf16x8 vf10 = *(const bf16x8*)(vb1 + k0);        // d 16-31, keys k0..k0+31
        bf16x8 vf01 = *(const bf16x8*)(vb0 + k0 + 32);   // d 0-15,  keys +32..63
        bf16x8 vf11 = *(const bf16x8*)(vb1 + k0 + 32);

        f32x4 s0 = __builtin_amdgcn_mfma_f32_16x16x32_bf16(kf0, qf, zero, 0, 0, 0);
        f32x4 s1 = __builtin_amdgcn_mfma_f32_16x16x32_bf16(kf1, qf, zero, 0, 0, 0);
        f32x4 s2 = __builtin_amdgcn_mfma_f32_16x16x32_bf16(kf2, qf, zero, 0, 0, 0);
        f32x4 s3 = __builtin_amdgcn_mfma_f32_16x16x32_bf16(kf3, qf, zero, 0, 0, 0);

        // exp2 + pack + wave-private LDS write (keys t*16+4q..+3 at row m16)
        f32x4 st[4] = {s0, s1, s2, s3};
        #pragma unroll
        for (int t = 0; t < 4; t++) {
            float p0 = fexp2(st[t][0]);
            float p1 = fexp2(st[t][1]);
            float p2 = fexp2(st[t][2]);
            float p3 = fexp2(st[t][3]);
            lp += (p0 + p1) + (p2 + p3);
            *(uint2*)(prow + 16 * t + 4 * quad) =
                make_uint2(pack_bf16(p0, p1), pack_bf16(p2, p3));
        }
        asm volatile("s_waitcnt lgkmcnt(0)" ::: "memory");
        // P B-frags: B[k=key=quad*8+j][n=query=lane&15]
        bf16x8 pf0 = *(const bf16x8*)(prow + 8 * quad);
        bf16x8 pf1 = *(const bf16x8*)(prow + 32 + 8 * quad);
        oacc0 = __builtin_amdgcn_mfma_f32_16x16x32_bf16(vf00, pf0, oacc0, 0, 0, 0);
        oacc1 = __builtin_amdgcn_mfma_f32_16x16x32_bf16(vf10, pf0, oacc1, 0, 0, 0);
        oacc0 = __builtin_amdgcn_mfma_f32_16x16x32_bf16(vf01, pf1, oacc0, 0, 0, 0);
        oacc1 = __builtin_amdgcn_mfma_f32_16x16x32_bf16(vf11, pf1, oacc1, 0, 0, 0);
    }

    // per-query row sum: lanes q*16+m share query m -> reduce over q
    lp += __shfl_xor(lp, 16);
    lp += __shfl_xor(lp, 32);
    float inv = 1.0f / lp;

    // store O^T[d][l] bf16: lane(q,m) holds d={4q+r,16+4q+r}, l=l0+m (coalesced 32B runs)
    unsigned short* ob = attnb + (size_t)bh * HD * Lseq + l0 + m16;
    #pragma unroll
    for (int r = 0; r < 4; r++) {
        ob[(size_t)(4 * quad + r) * Lseq]      = f2bf(oacc0[r] * inv);
        ob[(size_t)(16 + 4 * quad + r) * Lseq] = f2bf(oacc1[r] * inv);
    }
}

// ---------------------------------------------------------------------------
// Kernel 3: output projection + bias + residual. attn input is bf16 (half the
// bytes); 32 outputs/thread => attn re-fetched x4 only.
// ---------------------------------------------------------------------------
__global__ __launch_bounds__(256) void proj_kernel(const unsigned short* __restrict__ attn,
        const float* __restrict__ w, const float* __restrict__ bias,
        const float* __restrict__ x, float* __restrict__ out) {
    int bid = blockIdx.x;
    int lt = bid & 7;            // 8 l-tiles of 256
    int og = (bid >> 3) & 3;     // 4 o-groups of 32
    int b  = bid >> 5;
    int l  = lt * 256 + threadIdx.x;
    int o0 = og * 32;
    float acc[32];
    #pragma unroll
    for (int i = 0; i < 32; i++) acc[i] = bias[o0 + i];
    const unsigned short* ab = attn + (size_t)b * Cdim * Lseq + l;
    #pragma unroll 4
    for (int c = 0; c < Cdim; c++) {
        float av = __builtin_bit_cast(float, (unsigned)ab[(size_t)c * Lseq] << 16);
        #pragma unroll
        for (int i = 0; i < 32; i++) acc[i] += w[(o0 + i) * Cdim + c] * av;
    }
    const float* xb = x + ((size_t)b * Cdim + o0) * Lseq + l;
    float* ob = out + ((size_t)b * Cdim + o0) * Lseq + l;
    #pragma unroll
    for (int i = 0; i < 32; i++) ob[(size_t)i * Lseq] = acc[i] + xb[(size_t)i * Lseq];
}

extern "C" void kernel_launch(void* const* d_in, const int* in_sizes, int n_in,
                              void* d_out, int out_size, void* d_ws, size_t ws_size,
                              hipStream_t stream) {
    const float* x      = (const float*)d_in[0];
    const float* w_qkv  = (const float*)d_in[1];
    const float* b_qkv  = (const float*)d_in[2];
    const float* w_proj = (const float*)d_in[3];
    const float* b_proj = (const float*)d_in[4];
    float* out = (float*)d_out;

    // ws: qh 4MB | kh 4MB | vh 4MB | attnb 4MB (all bf16)
    const size_t QKV_ELEMS = (size_t)BH * Lseq * HD;   // 2M
    unsigned short* qh = (unsigned short*)d_ws;
    unsigned short* kh = qh + QKV_ELEMS;
    unsigned short* vh = kh + QKV_ELEMS;
    unsigned short* attnb = vh + QKV_ELEMS;

    qkv_kernel<<<dim3(512), dim3(256), 0, stream>>>(x, w_qkv, b_qkv, qh, kh, vh);
    attn_kernel<<<dim3(BH * 32), dim3(256), 0, stream>>>(qh, kh, vh, attnb);
    proj_kernel<<<dim3(256), dim3(256), 0, stream>>>(attnb, w_proj, b_proj, x, out);
}

// Round 5
// 197.841 us; speedup vs baseline: 1.3756x; 1.3756x over previous
//
#include <hip/hip_runtime.h>

// Problem constants: B=8, C=128, L=2048, H=4, D=32
#define Bsz 8
#define Cdim 128
#define Lseq 2048
#define NH 4
#define HD 32
#define BH 32
// 1/sqrt(D) * log2(e): scores feed v_exp_f32 (2^x) directly
#define QSCALE (0.17677669529663687f * 1.4426950408889634f)

typedef __bf16 bf16x8 __attribute__((ext_vector_type(8)));
typedef __bf16 bf16x4 __attribute__((ext_vector_type(4)));
typedef float f32x4 __attribute__((ext_vector_type(4)));

__device__ __forceinline__ float fexp2(float x) {
#if __has_builtin(__builtin_amdgcn_exp2f)
    return __builtin_amdgcn_exp2f(x);
#else
    return __expf(x * 0.6931471805599453f);
#endif
}

__device__ __forceinline__ unsigned short f2bf(float f) {   // RNE
    unsigned u = __builtin_bit_cast(unsigned, f);
    u += 0x7FFFu + ((u >> 16) & 1u);
    return (unsigned short)(u >> 16);
}

__device__ __forceinline__ unsigned pack_bf16(float a, float b) {  // RNE pair
    return (unsigned)f2bf(a) | ((unsigned)f2bf(b) << 16);
}

// RTZ pack of two f32 -> packed bf16x2, single v_perm_b32.
// result low16 = hi16(a), high16 = hi16(b)
__device__ __forceinline__ unsigned pack_bf16_rtz(float a, float b) {
    return __builtin_amdgcn_perm(__builtin_bit_cast(unsigned, b),
                                 __builtin_bit_cast(unsigned, a), 0x07060302u);
}

#define MFMA16(A, B, C) __builtin_amdgcn_mfma_f32_16x16x32_bf16((A), (B), (C), 0, 0, 0)

// ---------------------------------------------------------------------------
// Kernel 0: prep. blocks 0..255: transpose x [B][C][L] fp32 -> xT [B][L][C]
// bf16 via LDS (stride 132: 2-way-only conflicts). blocks 256/257: convert
// w_qkv / w_proj fp32 -> bf16 (RNE).
// ---------------------------------------------------------------------------
__global__ __launch_bounds__(256) void prep_kernel(const float* __restrict__ x,
        const float* __restrict__ w_qkv, const float* __restrict__ w_proj,
        unsigned short* __restrict__ xT, unsigned short* __restrict__ wqb,
        unsigned short* __restrict__ wpb) {
    int bid = blockIdx.x;
    int t = threadIdx.x;
    if (bid < 256) {
        __shared__ __attribute__((aligned(16))) unsigned short T[64][132];
        int b = bid >> 5;
        int l0 = (bid & 31) * 64;
        int ll = t & 63, cg = t >> 6;
        #pragma unroll 8
        for (int i = 0; i < 32; i++) {
            int c = cg * 32 + i;
            T[ll][c] = f2bf(x[((size_t)b * Cdim + c) * Lseq + l0 + ll]);
        }
        __syncthreads();
        int l = t >> 2, cc = (t & 3) * 32;
        unsigned short* dst = xT + ((size_t)b * Lseq + l0 + l) * Cdim + cc;
        #pragma unroll
        for (int j = 0; j < 8; j++)
            *(uint2*)(dst + j * 4) = *(const uint2*)(&T[l][cc + j * 4]);
    } else if (bid == 256) {
        const float2* s = (const float2*)w_qkv;
        unsigned* d = (unsigned*)wqb;
        for (int i = t; i < 3 * Cdim * Cdim / 2; i += 256) {
            float2 f = s[i];
            d[i] = pack_bf16(f.x, f.y);
        }
    } else {
        const float2* s = (const float2*)w_proj;
        unsigned* d = (unsigned*)wpb;
        for (int i = t; i < Cdim * Cdim / 2; i += 256) {
            float2 f = s[i];
            d[i] = pack_bf16(f.x, f.y);
        }
    }
}

// ---------------------------------------------------------------------------
// Kernel 1: QKV projection as bf16 MFMA GEMM.  D[o][n] = wq[o][:]·xT[n][:]
// A = wq [384][128], B = xT [16384][128] (both k-contiguous 16B frags).
// Block: 64 o x 128 n; wave: 16 o x 128 n (8 sub-tiles, K=128 in 4 MFMA steps).
// Epilogue: +bias, Q scaled; Q,K -> [bh][l][32], V -> [bh][32][l].
// ---------------------------------------------------------------------------
__global__ __launch_bounds__(256) void qkv_kernel(const unsigned short* __restrict__ wq,
        const unsigned short* __restrict__ xT, const float* __restrict__ bias,
        unsigned short* __restrict__ qh, unsigned short* __restrict__ kh,
        unsigned short* __restrict__ vh) {
    int bid = blockIdx.x;
    int ot = bid % 6;
    int nt = bid / 6;                 // 0..127
    int lane = threadIdx.x & 63;
    int wv = threadIdx.x >> 6;
    int m16 = lane & 15, quad = lane >> 4;
    int o0 = ot * 64 + wv * 16;
    int n0 = nt * 128;

    bf16x8 af[4];
    #pragma unroll
    for (int ks = 0; ks < 4; ks++)
        af[ks] = *(const bf16x8*)(wq + (size_t)(o0 + m16) * Cdim + ks * 32 + quad * 8);
    float bs[4];
    #pragma unroll
    for (int r = 0; r < 4; r++) bs[r] = bias[o0 + quad * 4 + r];
    int oq = o0 + quad * 4;

    for (int lt2 = 0; lt2 < 8; lt2++) {
        int n = n0 + lt2 * 16 + m16;
        f32x4 acc = {0.f, 0.f, 0.f, 0.f};
        #pragma unroll
        for (int ks = 0; ks < 4; ks++) {
            bf16x8 bx = *(const bf16x8*)(xT + (size_t)n * Cdim + ks * 32 + quad * 8);
            acc = MFMA16(af[ks], bx, acc);
        }
        int b = n >> 11, l = n & (Lseq - 1);
        if (ot < 2) {            // Q (scaled)
            #pragma unroll
            for (int r = 0; r < 4; r++) {
                int o = oq + r, h = o >> 5, d = o & 31;
                qh[((size_t)(b * NH + h) * Lseq + l) * HD + d] =
                    f2bf((acc[r] + bs[r]) * QSCALE);
            }
        } else if (ot < 4) {     // K
            #pragma unroll
            for (int r = 0; r < 4; r++) {
                int o = oq + r - Cdim, h = o >> 5, d = o & 31;
                kh[((size_t)(b * NH + h) * Lseq + l) * HD + d] = f2bf(acc[r] + bs[r]);
            }
        } else {                 // V, layout [bh][d][l]
            #pragma unroll
            for (int r = 0; r < 4; r++) {
                int o = oq + r - 2 * Cdim, h = o >> 5, d = o & 31;
                vh[((size_t)(b * NH + h) * HD + d) * Lseq + l] = f2bf(acc[r] + bs[r]);
            }
        }
    }
}

// ---------------------------------------------------------------------------
// Kernel 2: MFMA flash attention, software-pipelined, barrier-free.
//   S' = K·Q^T (A=K, B=Q), exp2, perm-pack (RTZ), P via wave-private LDS
//   (stride 68, all-b64 ops: conflict-free), O^T = V·P^T, row-sums via
//   ones-A MFMA. Iteration overlap: consume P(it-1) while computing S(it);
//   prefetch K/V(it+1). Single buffer safe (read precedes overwrite, per-wave
//   LDS is FIFO). Output -> attnb [b][l][128] bf16 (c-contiguous for proj).
// ---------------------------------------------------------------------------
__global__ __launch_bounds__(256) void attn_kernel(
        const unsigned short* __restrict__ qh, const unsigned short* __restrict__ kh,
        const unsigned short* __restrict__ vh, unsigned short* __restrict__ attnb) {
    __shared__ __attribute__((aligned(16))) unsigned short plds[4][16][68];

    int bid = blockIdx.x;
    int xcd  = bid & 7;                 // same bh -> same XCD (K/V L2 residency)
    int rest = bid >> 3;
    int qt = rest & 31;
    int bh = xcd + 8 * (rest >> 5);

    int lane = threadIdx.x & 63;
    int wv   = threadIdx.x >> 6;
    int m16  = lane & 15;
    int quad = lane >> 4;
    int l0 = qt * 64 + wv * 16;

    // Q B-frag: B[k=d=quad*8+j][n=query=m16]
    bf16x8 qf = *(const bf16x8*)(qh + ((size_t)bh * Lseq + l0 + m16) * HD + quad * 8);

    bf16x8 ones;
    #pragma unroll
    for (int i = 0; i < 8; i++) ones[i] = (__bf16)1.0f;

    const unsigned short* kb = kh + (size_t)bh * Lseq * HD + m16 * HD + quad * 8;
    const unsigned short* vb = vh + (size_t)bh * HD * Lseq + m16 * Lseq + quad * 8;

    f32x4 oacc0 = {0.f, 0.f, 0.f, 0.f};
    f32x4 oacc1 = {0.f, 0.f, 0.f, 0.f};
    f32x4 lacc  = {0.f, 0.f, 0.f, 0.f};
    f32x4 zero  = {0.f, 0.f, 0.f, 0.f};
    unsigned short* prow = &plds[wv][m16][0];

    // ---- prologue: chunk 0 ----
    bf16x8 kf[4], vf[4], vfN[4];
    #pragma unroll
    for (int t = 0; t < 4; t++) kf[t] = *(const bf16x8*)(kb + t * 16 * HD);
    vf[0] = *(const bf16x8*)(vb);                    // d 0-15,  keys lo32
    vf[1] = *(const bf16x8*)(vb + 16 * Lseq);        // d 16-31, keys lo32
    vf[2] = *(const bf16x8*)(vb + 32);               // d 0-15,  keys hi32
    vf[3] = *(const bf16x8*)(vb + 16 * Lseq + 32);   // d 16-31, keys hi32

    #pragma unroll
    for (int t = 0; t < 4; t++) {
        f32x4 s = MFMA16(kf[t], qf, zero);
        unsigned u0 = pack_bf16_rtz(fexp2(s[0]), fexp2(s[1]));
        unsigned u1 = pack_bf16_rtz(fexp2(s[2]), fexp2(s[3]));
        *(uint2*)(prow + 16 * t + 4 * quad) = make_uint2(u0, u1);
    }
    // prefetch chunk 1
    #pragma unroll
    for (int t = 0; t < 4; t++) kf[t] = *(const bf16x8*)(kb + 64 * HD + t * 16 * HD);
    vfN[0] = *(const bf16x8*)(vb + 64);
    vfN[1] = *(const bf16x8*)(vb + 16 * Lseq + 64);
    vfN[2] = *(const bf16x8*)(vb + 96);
    vfN[3] = *(const bf16x8*)(vb + 16 * Lseq + 96);

    for (int it = 1; it < Lseq / 64; it++) {
        // S for chunk it (issue MFMAs early)
        f32x4 s[4];
        #pragma unroll
        for (int t = 0; t < 4; t++) s[t] = MFMA16(kf[t], qf, zero);

        // consume P(it-1) — written a full iteration ago, waits are cheap
        bf16x4 a0 = *(const bf16x4*)(prow + 8 * quad);
        bf16x4 a1 = *(const bf16x4*)(prow + 8 * quad + 4);
        bf16x8 pf0 = __builtin_shufflevector(a0, a1, 0, 1, 2, 3, 4, 5, 6, 7);
        bf16x4 b0 = *(const bf16x4*)(prow + 32 + 8 * quad);
        bf16x4 b1 = *(const bf16x4*)(prow + 36 + 8 * quad);
        bf16x8 pf1 = __builtin_shufflevector(b0, b1, 0, 1, 2, 3, 4, 5, 6, 7);
        oacc0 = MFMA16(vf[0], pf0, oacc0);
        oacc1 = MFMA16(vf[1], pf0, oacc1);
        oacc0 = MFMA16(vf[2], pf1, oacc0);
        oacc1 = MFMA16(vf[3], pf1, oacc1);
        lacc  = MFMA16(ones, pf0, lacc);
        lacc  = MFMA16(ones, pf1, lacc);
        #pragma unroll
        for (int t = 0; t < 4; t++) vf[t] = vfN[t];

        // produce P(it) — after the reads above, single buffer is safe
        #pragma unroll
        for (int t = 0; t < 4; t++) {
            unsigned u0 = pack_bf16_rtz(fexp2(s[t][0]), fexp2(s[t][1]));
            unsigned u1 = pack_bf16_rtz(fexp2(s[t][2]), fexp2(s[t][3]));
            *(uint2*)(prow + 16 * t + 4 * quad) = make_uint2(u0, u1);
        }

        // prefetch chunk it+1 (last iter reads past kh/vh into ws — safe)
        const unsigned short* kbi = kb + (size_t)(it + 1) * 64 * HD;
        #pragma unroll
        for (int t = 0; t < 4; t++) kf[t] = *(const bf16x8*)(kbi + t * 16 * HD);
        const unsigned short* vbi = vb + (it + 1) * 64;
        vfN[0] = *(const bf16x8*)(vbi);
        vfN[1] = *(const bf16x8*)(vbi + 16 * Lseq);
        vfN[2] = *(const bf16x8*)(vbi + 32);
        vfN[3] = *(const bf16x8*)(vbi + 16 * Lseq + 32);
    }

    // epilogue: consume P(31)
    {
        bf16x4 a0 = *(const bf16x4*)(prow + 8 * quad);
        bf16x4 a1 = *(const bf16x4*)(prow + 8 * quad + 4);
        bf16x8 pf0 = __builtin_shufflevector(a0, a1, 0, 1, 2, 3, 4, 5, 6, 7);
        bf16x4 b0 = *(const bf16x4*)(prow + 32 + 8 * quad);
        bf16x4 b1 = *(const bf16x4*)(prow + 36 + 8 * quad);
        bf16x8 pf1 = __builtin_shufflevector(b0, b1, 0, 1, 2, 3, 4, 5, 6, 7);
        oacc0 = MFMA16(vf[0], pf0, oacc0);
        oacc1 = MFMA16(vf[1], pf0, oacc1);
        oacc0 = MFMA16(vf[2], pf1, oacc0);
        oacc1 = MFMA16(vf[3], pf1, oacc1);
        lacc  = MFMA16(ones, pf0, lacc);
        lacc  = MFMA16(ones, pf1, lacc);
    }

    // lacc rows are replicated rowsums per query=m16; normalize and store.
    float inv = 1.0f / lacc[0];
    int b = bh >> 2, h = bh & 3;
    unsigned short* ob = attnb + ((size_t)b * Lseq + l0 + m16) * Cdim + h * HD + 4 * quad;
    uint2 u;
    u.x = pack_bf16(oacc0[0] * inv, oacc0[1] * inv);
    u.y = pack_bf16(oacc0[2] * inv, oacc0[3] * inv);
    *(uint2*)ob = u;
    u.x = pack_bf16(oacc1[0] * inv, oacc1[1] * inv);
    u.y = pack_bf16(oacc1[2] * inv, oacc1[3] * inv);
    *(uint2*)(ob + 16) = u;
}

// ---------------------------------------------------------------------------
// Kernel 3: output projection as bf16 MFMA GEMM + bias + residual (fp32 out).
// A = wp [128][128] bf16, B = attnb [16384][128] bf16. Block: 64 o x 64 n.
// ---------------------------------------------------------------------------
__global__ __launch_bounds__(256) void proj_kernel(const unsigned short* __restrict__ wp,
        const unsigned short* __restrict__ attnb, const float* __restrict__ bias,
        const float* __restrict__ x, float* __restrict__ out) {
    int bid = blockIdx.x;
    int ot = bid & 1;
    int nt = bid >> 1;                // 0..255
    int lane = threadIdx.x & 63;
    int wv = threadIdx.x >> 6;
    int m16 = lane & 15, quad = lane >> 4;
    int o0 = ot * 64 + wv * 16;
    int n0 = nt * 64;

    bf16x8 af[4];
    #pragma unroll
    for (int ks = 0; ks < 4; ks++)
        af[ks] = *(const bf16x8*)(wp + (size_t)(o0 + m16) * Cdim + ks * 32 + quad * 8);
    float bs[4];
    #pragma unroll
    for (int r = 0; r < 4; r++) bs[r] = bias[o0 + quad * 4 + r];
    int oq = o0 + quad * 4;

    for (int lt2 = 0; lt2 < 4; lt2++) {
        int n = n0 + lt2 * 16 + m16;
        f32x4 acc = {0.f, 0.f, 0.f, 0.f};
        #pragma unroll
        for (int ks = 0; ks < 4; ks++) {
            bf16x8 bx = *(const bf16x8*)(attnb + (size_t)n * Cdim + ks * 32 + quad * 8);
            acc = MFMA16(af[ks], bx, acc);
        }
        int b = n >> 11, l = n & (Lseq - 1);
        #pragma unroll
        for (int r = 0; r < 4; r++) {
            size_t xi = ((size_t)b * Cdim + oq + r) * Lseq + l;
            out[xi] = acc[r] + bs[r] + x[xi];
        }
    }
}

extern "C" void kernel_launch(void* const* d_in, const int* in_sizes, int n_in,
                              void* d_out, int out_size, void* d_ws, size_t ws_size,
                              hipStream_t stream) {
    const float* x      = (const float*)d_in[0];
    const float* w_qkv  = (const float*)d_in[1];
    const float* b_qkv  = (const float*)d_in[2];
    const float* w_proj = (const float*)d_in[3];
    const float* b_proj = (const float*)d_in[4];
    float* out = (float*)d_out;

    // ws (ushorts): qh 2M | kh 2M | vh 2M | attnb 2M | xT 2M | wqb 49152 | wpb 16384
    const size_t E = (size_t)BH * Lseq * HD;   // 2M elems = 4 MB
    unsigned short* qh    = (unsigned short*)d_ws;
    unsigned short* kh    = qh + E;
    unsigned short* vh    = kh + E;
    unsigned short* attnb = vh + E;
    unsigned short* xT    = attnb + E;
    unsigned short* wqb   = xT + E;
    unsigned short* wpb   = wqb + 3 * Cdim * Cdim;

    prep_kernel<<<dim3(258), dim3(256), 0, stream>>>(x, w_qkv, w_proj, xT, wqb, wpb);
    qkv_kernel<<<dim3(768), dim3(256), 0, stream>>>(wqb, xT, b_qkv, qh, kh, vh);
    attn_kernel<<<dim3(BH * 32), dim3(256), 0, stream>>>(qh, kh, vh, attnb);
    proj_kernel<<<dim3(512), dim3(256), 0, stream>>>(wpb, attnb, b_proj, x, out);
}

// Round 6
// 147.915 us; speedup vs baseline: 1.8400x; 1.3375x over previous
//
#include <hip/hip_runtime.h>

// Problem constants: B=8, C=128, L=2048, H=4, D=32
#define Bsz 8
#define Cdim 128
#define Lseq 2048
#define NH 4
#define HD 32
#define BH 32
// 1/sqrt(D) * log2(e): scores feed v_exp_f32 (2^x) directly
#define QSCALE (0.17677669529663687f * 1.4426950408889634f)

typedef __bf16 bf16x8 __attribute__((ext_vector_type(8)));
typedef __bf16 bf16x4 __attribute__((ext_vector_type(4)));
typedef float f32x4 __attribute__((ext_vector_type(4)));

__device__ __forceinline__ float fexp2(float x) {
#if __has_builtin(__builtin_amdgcn_exp2f)
    return __builtin_amdgcn_exp2f(x);
#else
    return __expf(x * 0.6931471805599453f);
#endif
}

__device__ __forceinline__ unsigned short f2bf(float f) {   // RNE
    unsigned u = __builtin_bit_cast(unsigned, f);
    u += 0x7FFFu + ((u >> 16) & 1u);
    return (unsigned short)(u >> 16);
}

__device__ __forceinline__ unsigned pack_bf16(float a, float b) {  // RNE pair
    return (unsigned)f2bf(a) | ((unsigned)f2bf(b) << 16);
}

// RTZ pack of two f32 -> packed bf16x2, single v_perm_b32.
__device__ __forceinline__ unsigned pack_bf16_rtz(float a, float b) {
    return __builtin_amdgcn_perm(__builtin_bit_cast(unsigned, b),
                                 __builtin_bit_cast(unsigned, a), 0x07060302u);
}

#define MFMA16(A, B, C) __builtin_amdgcn_mfma_f32_16x16x32_bf16((A), (B), (C), 0, 0, 0)

// ---------------------------------------------------------------------------
// Kernel 0: prep. blocks 0..255: transpose x [B][C][L] fp32 -> xT [B][L][C]
// bf16 via LDS. blocks 256/257: convert w_qkv / w_proj fp32 -> bf16 (RNE).
// ---------------------------------------------------------------------------
__global__ __launch_bounds__(256) void prep_kernel(const float* __restrict__ x,
        const float* __restrict__ w_qkv, const float* __restrict__ w_proj,
        unsigned short* __restrict__ xT, unsigned short* __restrict__ wqb,
        unsigned short* __restrict__ wpb) {
    int bid = blockIdx.x;
    int t = threadIdx.x;
    if (bid < 256) {
        __shared__ __attribute__((aligned(16))) unsigned short T[64][132];
        int b = bid >> 5;
        int l0 = (bid & 31) * 64;
        int ll = t & 63, cg = t >> 6;
        #pragma unroll 8
        for (int i = 0; i < 32; i++) {
            int c = cg * 32 + i;
            T[ll][c] = f2bf(x[((size_t)b * Cdim + c) * Lseq + l0 + ll]);
        }
        __syncthreads();
        int l = t >> 2, cc = (t & 3) * 32;
        unsigned short* dst = xT + ((size_t)b * Lseq + l0 + l) * Cdim + cc;
        #pragma unroll
        for (int j = 0; j < 8; j++)
            *(uint2*)(dst + j * 4) = *(const uint2*)(&T[l][cc + j * 4]);
    } else if (bid == 256) {
        const float2* s = (const float2*)w_qkv;
        unsigned* d = (unsigned*)wqb;
        for (int i = t; i < 3 * Cdim * Cdim / 2; i += 256) {
            float2 f = s[i];
            d[i] = pack_bf16(f.x, f.y);
        }
    } else {
        const float2* s = (const float2*)w_proj;
        unsigned* d = (unsigned*)wpb;
        for (int i = t; i < Cdim * Cdim / 2; i += 256) {
            float2 f = s[i];
            d[i] = pack_bf16(f.x, f.y);
        }
    }
}

// ---------------------------------------------------------------------------
// Kernel 1: QKV projection as bf16 MFMA GEMM.  D[o][n] = wq[o][:]·xT[n][:]
// Q,K -> [bh][l][32]; V -> tiled [bh][kc64][d32][kk64] (see attn V-frag note).
// ---------------------------------------------------------------------------
__global__ __launch_bounds__(256) void qkv_kernel(const unsigned short* __restrict__ wq,
        const unsigned short* __restrict__ xT, const float* __restrict__ bias,
        unsigned short* __restrict__ qh, unsigned short* __restrict__ kh,
        unsigned short* __restrict__ vh) {
    int bid = blockIdx.x;
    int ot = bid % 6;
    int nt = bid / 6;                 // 0..127
    int lane = threadIdx.x & 63;
    int wv = threadIdx.x >> 6;
    int m16 = lane & 15, quad = lane >> 4;
    int o0 = ot * 64 + wv * 16;
    int n0 = nt * 128;

    bf16x8 af[4];
    #pragma unroll
    for (int ks = 0; ks < 4; ks++)
        af[ks] = *(const bf16x8*)(wq + (size_t)(o0 + m16) * Cdim + ks * 32 + quad * 8);
    float bs[4];
    #pragma unroll
    for (int r = 0; r < 4; r++) bs[r] = bias[o0 + quad * 4 + r];
    int oq = o0 + quad * 4;

    for (int lt2 = 0; lt2 < 8; lt2++) {
        int n = n0 + lt2 * 16 + m16;
        f32x4 acc = {0.f, 0.f, 0.f, 0.f};
        #pragma unroll
        for (int ks = 0; ks < 4; ks++) {
            bf16x8 bx = *(const bf16x8*)(xT + (size_t)n * Cdim + ks * 32 + quad * 8);
            acc = MFMA16(af[ks], bx, acc);
        }
        int b = n >> 11, l = n & (Lseq - 1);
        if (ot < 2) {            // Q (scaled)
            #pragma unroll
            for (int r = 0; r < 4; r++) {
                int o = oq + r, h = o >> 5, d = o & 31;
                qh[((size_t)(b * NH + h) * Lseq + l) * HD + d] =
                    f2bf((acc[r] + bs[r]) * QSCALE);
            }
        } else if (ot < 4) {     // K
            #pragma unroll
            for (int r = 0; r < 4; r++) {
                int o = oq + r - Cdim, h = o >> 5, d = o & 31;
                kh[((size_t)(b * NH + h) * Lseq + l) * HD + d] = f2bf(acc[r] + bs[r]);
            }
        } else {                 // V tiled: [bh][kc][d][kk], kc=l>>6, kk=l&63
            #pragma unroll
            for (int r = 0; r < 4; r++) {
                int o = oq + r - 2 * Cdim, h = o >> 5, d = o & 31;
                int kc = l >> 6, kk = l & 63;
                vh[(((size_t)(b * NH + h) * 32 + kc) * HD + d) * 64 + kk] =
                    f2bf(acc[r] + bs[r]);
            }
        }
    }
}

// ---------------------------------------------------------------------------
// Kernel 2: MFMA flash attention, key-split across waves.
// Block = 64 q-rows of one (b,h); wave wv handles ALL 64 q x keys
// [wv*512,(wv+1)*512) -> zero intra-block K/V load redundancy (4x traffic
// cut vs q-split) and 32 MFMAs per 8KB of K/V (was 10).
// V tiled [bh][kc][d][kk]: frag rows stride 128B (no L1 set aliasing; each
// wave-load = 16 full 64B lines in a 2KB window).
// Per 64-key chunk: 16 QK MFMAs -> exp2 -> RTZ pack -> wave-private LDS
// (stride 68, conflict-free, no barriers) -> 16 PV MFMAs into O^T partials.
// End: per-wave partials combined via LDS (2 barriers), normalized, stored.
// ---------------------------------------------------------------------------
__global__ __launch_bounds__(256, 4) void attn_kernel(
        const unsigned short* __restrict__ qh, const unsigned short* __restrict__ kh,
        const unsigned short* __restrict__ vh, unsigned short* __restrict__ attnb) {
    // phase 1: per-wave P tiles  [64][68] ushort @ wv*8704   (34816 B)
    // phase 2: red_o [4][64][36] float (36864 B) + red_l [4][64] float @36864
    __shared__ __attribute__((aligned(16))) char smem[37888];

    int bid = blockIdx.x;
    int xcd  = bid & 7;                 // same bh -> same XCD (K/V L2 residency)
    int rest = bid >> 3;
    int qt = rest & 31;
    int bh = xcd + 8 * (rest >> 5);

    int lane = threadIdx.x & 63;
    int wv   = threadIdx.x >> 6;
    int m16  = lane & 15;
    int quad = lane >> 4;
    int l0 = qt * 64;

    unsigned short (*plds)[68] = (unsigned short (*)[68])(smem + wv * 8704);

    // Q B-frags for the 4 q-subtiles (all 64 q-rows)
    bf16x8 qf[4];
    #pragma unroll
    for (int qs = 0; qs < 4; qs++)
        qf[qs] = *(const bf16x8*)(qh + ((size_t)bh * Lseq + l0 + qs * 16 + m16) * HD + quad * 8);

    f32x4 oacc[4][2];
    #pragma unroll
    for (int qs = 0; qs < 4; qs++) {
        oacc[qs][0] = f32x4{0.f, 0.f, 0.f, 0.f};
        oacc[qs][1] = f32x4{0.f, 0.f, 0.f, 0.f};
    }
    float lsum[4] = {0.f, 0.f, 0.f, 0.f};
    f32x4 zero = {0.f, 0.f, 0.f, 0.f};

    for (int it = 0; it < 8; it++) {
        int k0 = wv * 512 + it * 64;
        int kc = k0 >> 6;
        // K A-frags: A[m=key][k=d], rows stride 64B (benign)
        bf16x8 kf[4];
        #pragma unroll
        for (int t = 0; t < 4; t++)
            kf[t] = *(const bf16x8*)(kh + ((size_t)bh * Lseq + k0 + 16 * t + m16) * HD + quad * 8);
        // V A-frags from tiled layout: A[m=d][k=key-within-chunk]
        const unsigned short* vbase =
            vh + (((size_t)bh * 32 + kc) * HD + m16) * 64 + quad * 8;
        bf16x8 vf0 = *(const bf16x8*)(vbase);                 // d 0-15,  keys 0-31
        bf16x8 vf1 = *(const bf16x8*)(vbase + 16 * 64);       // d 16-31, keys 0-31
        bf16x8 vf2 = *(const bf16x8*)(vbase + 32);            // d 0-15,  keys 32-63
        bf16x8 vf3 = *(const bf16x8*)(vbase + 16 * 64 + 32);  // d 16-31, keys 32-63

        // S = K·Q^T per q-subtile -> exp2 -> pack -> wave-private LDS
        #pragma unroll
        for (int qs = 0; qs < 4; qs++) {
            f32x4 s[4];
            #pragma unroll
            for (int t = 0; t < 4; t++) s[t] = MFMA16(kf[t], qf[qs], zero);
            unsigned short* prow = &plds[qs * 16 + m16][0];
            float ls = 0.f;
            #pragma unroll
            for (int t = 0; t < 4; t++) {
                float p0 = fexp2(s[t][0]);
                float p1 = fexp2(s[t][1]);
                float p2 = fexp2(s[t][2]);
                float p3 = fexp2(s[t][3]);
                ls += (p0 + p1) + (p2 + p3);
                *(uint2*)(prow + 16 * t + 4 * quad) =
                    make_uint2(pack_bf16_rtz(p0, p1), pack_bf16_rtz(p2, p3));
            }
            lsum[qs] += ls;
        }

        // PV: O^T += V·P^T per q-subtile (same-wave LDS dep, compiler waits)
        #pragma unroll
        for (int qs = 0; qs < 4; qs++) {
            const unsigned short* prow = &plds[qs * 16 + m16][0];
            bf16x4 a0 = *(const bf16x4*)(prow + 8 * quad);
            bf16x4 a1 = *(const bf16x4*)(prow + 8 * quad + 4);
            bf16x8 pf0 = __builtin_shufflevector(a0, a1, 0, 1, 2, 3, 4, 5, 6, 7);
            bf16x4 b0 = *(const bf16x4*)(prow + 32 + 8 * quad);
            bf16x4 b1 = *(const bf16x4*)(prow + 36 + 8 * quad);
            bf16x8 pf1 = __builtin_shufflevector(b0, b1, 0, 1, 2, 3, 4, 5, 6, 7);
            oacc[qs][0] = MFMA16(vf0, pf0, oacc[qs][0]);
            oacc[qs][1] = MFMA16(vf1, pf0, oacc[qs][1]);
            oacc[qs][0] = MFMA16(vf2, pf1, oacc[qs][0]);
            oacc[qs][1] = MFMA16(vf3, pf1, oacc[qs][1]);
        }
    }

    // full per-wave rowsum for query m16 (reduce over quads)
    #pragma unroll
    for (int qs = 0; qs < 4; qs++) {
        float v = lsum[qs];
        v += __shfl_xor(v, 16);
        v += __shfl_xor(v, 32);
        lsum[qs] = v;
    }

    __syncthreads();   // all waves done reading their plds; smem is repurposed

    float (*red_o)[36] = (float (*)[36])(smem + wv * 9216);
    float* red_l = (float*)(smem + 36864) + wv * 64;
    #pragma unroll
    for (int qs = 0; qs < 4; qs++) {
        int row = qs * 16 + m16;
        #pragma unroll
        for (int r = 0; r < 4; r++) {
            red_o[row][4 * quad + r]      = oacc[qs][0][r];
            red_o[row][16 + 4 * quad + r] = oacc[qs][1][r];
        }
        if (quad == 0) red_l[row] = lsum[qs];
    }
    __syncthreads();

    // combine across waves: thread -> (q=t>>2, 8 d's), normalize, store bf16
    int q = threadIdx.x >> 2;
    int d0 = (threadIdx.x & 3) * 8;
    float a8[8] = {0.f, 0.f, 0.f, 0.f, 0.f, 0.f, 0.f, 0.f};
    float lt = 0.f;
    #pragma unroll
    for (int w = 0; w < 4; w++) {
        const float* ro = (const float*)(smem + w * 9216) + q * 36 + d0;
        #pragma unroll
        for (int j = 0; j < 8; j++) a8[j] += ro[j];
        lt += ((const float*)(smem + 36864))[w * 64 + q];
    }
    float inv = 1.0f / lt;
    int b = bh >> 2, h = bh & 3;
    unsigned short* ob = attnb + ((size_t)b * Lseq + l0 + q) * Cdim + h * HD + d0;
    uint4 u;
    u.x = pack_bf16(a8[0] * inv, a8[1] * inv);
    u.y = pack_bf16(a8[2] * inv, a8[3] * inv);
    u.z = pack_bf16(a8[4] * inv, a8[5] * inv);
    u.w = pack_bf16(a8[6] * inv, a8[7] * inv);
    *(uint4*)ob = u;
}

// ---------------------------------------------------------------------------
// Kernel 3: output projection as bf16 MFMA GEMM + bias + residual (fp32 out).
// ---------------------------------------------------------------------------
__global__ __launch_bounds__(256) void proj_kernel(const unsigned short* __restrict__ wp,
        const unsigned short* __restrict__ attnb, const float* __restrict__ bias,
        const float* __restrict__ x, float* __restrict__ out) {
    int bid = blockIdx.x;
    int ot = bid & 1;
    int nt = bid >> 1;                // 0..255
    int lane = threadIdx.x & 63;
    int wv = threadIdx.x >> 6;
    int m16 = lane & 15, quad = lane >> 4;
    int o0 = ot * 64 + wv * 16;
    int n0 = nt * 64;

    bf16x8 af[4];
    #pragma unroll
    for (int ks = 0; ks < 4; ks++)
        af[ks] = *(const bf16x8*)(wp + (size_t)(o0 + m16) * Cdim + ks * 32 + quad * 8);
    float bs[4];
    #pragma unroll
    for (int r = 0; r < 4; r++) bs[r] = bias[o0 + quad * 4 + r];
    int oq = o0 + quad * 4;

    for (int lt2 = 0; lt2 < 4; lt2++) {
        int n = n0 + lt2 * 16 + m16;
        f32x4 acc = {0.f, 0.f, 0.f, 0.f};
        #pragma unroll
        for (int ks = 0; ks < 4; ks++) {
            bf16x8 bx = *(const bf16x8*)(attnb + (size_t)n * Cdim + ks * 32 + quad * 8);
            acc = MFMA16(af[ks], bx, acc);
        }
        int b = n >> 11, l = n & (Lseq - 1);
        #pragma unroll
        for (int r = 0; r < 4; r++) {
            size_t xi = ((size_t)b * Cdim + oq + r) * Lseq + l;
            out[xi] = acc[r] + bs[r] + x[xi];
        }
    }
}

extern "C" void kernel_launch(void* const* d_in, const int* in_sizes, int n_in,
                              void* d_out, int out_size, void* d_ws, size_t ws_size,
                              hipStream_t stream) {
    const float* x      = (const float*)d_in[0];
    const float* w_qkv  = (const float*)d_in[1];
    const float* b_qkv  = (const float*)d_in[2];
    const float* w_proj = (const float*)d_in[3];
    const float* b_proj = (const float*)d_in[4];
    float* out = (float*)d_out;

    // ws (ushorts): qh 2M | kh 2M | vh 2M | attnb 2M | xT 2M | wqb 49152 | wpb 16384
    const size_t E = (size_t)BH * Lseq * HD;   // 2M elems = 4 MB
    unsigned short* qh    = (unsigned short*)d_ws;
    unsigned short* kh    = qh + E;
    unsigned short* vh    = kh + E;
    unsigned short* attnb = vh + E;
    unsigned short* xT    = attnb + E;
    unsigned short* wqb   = xT + E;
    unsigned short* wpb   = wqb + 3 * Cdim * Cdim;

    prep_kernel<<<dim3(258), dim3(256), 0, stream>>>(x, w_qkv, w_proj, xT, wqb, wpb);
    qkv_kernel<<<dim3(768), dim3(256), 0, stream>>>(wqb, xT, b_qkv, qh, kh, vh);
    attn_kernel<<<dim3(BH * 32), dim3(256), 0, stream>>>(qh, kh, vh, attnb);
    proj_kernel<<<dim3(512), dim3(256), 0, stream>>>(wpb, attnb, b_proj, x, out);
}

// Round 7
// 139.163 us; speedup vs baseline: 1.9557x; 1.0629x over previous
//
#include <hip/hip_runtime.h>

// Problem constants: B=8, C=128, L=2048, H=4, D=32
#define Bsz 8
#define Cdim 128
#define Lseq 2048
#define NH 4
#define HD 32
#define BH 32
// 1/sqrt(D) * log2(e): scores feed v_exp_f32 (2^x) directly
#define QSCALE (0.17677669529663687f * 1.4426950408889634f)

typedef __bf16 bf16x8 __attribute__((ext_vector_type(8)));
typedef __bf16 bf16x4 __attribute__((ext_vector_type(4)));
typedef float f32x4 __attribute__((ext_vector_type(4)));
typedef unsigned u32x4 __attribute__((ext_vector_type(4)));

__device__ __forceinline__ float fexp2(float x) {
#if __has_builtin(__builtin_amdgcn_exp2f)
    return __builtin_amdgcn_exp2f(x);
#else
    return __expf(x * 0.6931471805599453f);
#endif
}

__device__ __forceinline__ unsigned short f2bf(float f) {   // RNE
    unsigned u = __builtin_bit_cast(unsigned, f);
    u += 0x7FFFu + ((u >> 16) & 1u);
    return (unsigned short)(u >> 16);
}

__device__ __forceinline__ unsigned pack_bf16(float a, float b) {  // RNE pair
    return (unsigned)f2bf(a) | ((unsigned)f2bf(b) << 16);
}

// RTZ pack of two f32 -> packed bf16x2, single v_perm_b32.
__device__ __forceinline__ unsigned pack_bf16_rtz(float a, float b) {
    return __builtin_amdgcn_perm(__builtin_bit_cast(unsigned, b),
                                 __builtin_bit_cast(unsigned, a), 0x07060302u);
}

__device__ __forceinline__ float bf_lo(unsigned u) {
    return __builtin_bit_cast(float, u << 16);
}
__device__ __forceinline__ float bf_hi(unsigned u) {
    return __builtin_bit_cast(float, u & 0xFFFF0000u);
}

#define MFMA16(A, B, C) __builtin_amdgcn_mfma_f32_16x16x32_bf16((A), (B), (C), 0, 0, 0)

// ---------------------------------------------------------------------------
// Kernel 0: prep. blocks 0..255: transpose x [B][C][L] fp32 -> xT [B][L][C]
// bf16 via LDS. blocks 256..271: w_qkv fp32->bf16 (16-way). 272..279: w_proj.
// ---------------------------------------------------------------------------
__global__ __launch_bounds__(256) void prep_kernel(const float* __restrict__ x,
        const float* __restrict__ w_qkv, const float* __restrict__ w_proj,
        unsigned short* __restrict__ xT, unsigned short* __restrict__ wqb,
        unsigned short* __restrict__ wpb) {
    int bid = blockIdx.x;
    int t = threadIdx.x;
    if (bid < 256) {
        __shared__ __attribute__((aligned(16))) unsigned short T[64][132];
        int b = bid >> 5;
        int l0 = (bid & 31) * 64;
        int ll = t & 63, cg = t >> 6;
        #pragma unroll 8
        for (int i = 0; i < 32; i++) {
            int c = cg * 32 + i;
            T[ll][c] = f2bf(x[((size_t)b * Cdim + c) * Lseq + l0 + ll]);
        }
        __syncthreads();
        int l = t >> 2, cc = (t & 3) * 32;
        unsigned short* dst = xT + ((size_t)b * Lseq + l0 + l) * Cdim + cc;
        #pragma unroll
        for (int j = 0; j < 8; j++)
            *(uint2*)(dst + j * 4) = *(const uint2*)(&T[l][cc + j * 4]);
    } else if (bid < 272) {
        int base = (bid - 256) * 1536;          // 24576 float2 over 16 blocks
        const float2* s = (const float2*)w_qkv;
        unsigned* d = (unsigned*)wqb;
        for (int i = base + t; i < base + 1536; i += 256) {
            float2 f = s[i];
            d[i] = pack_bf16(f.x, f.y);
        }
    } else {
        int base = (bid - 272) * 1024;          // 8192 float2 over 8 blocks
        const float2* s = (const float2*)w_proj;
        unsigned* d = (unsigned*)wpb;
        for (int i = base + t; i < base + 1024; i += 256) {
            float2 f = s[i];
            d[i] = pack_bf16(f.x, f.y);
        }
    }
}

// ---------------------------------------------------------------------------
// Kernel 1: QKV projection as bf16 MFMA GEMM.  D[o][n] = wq[o][:]·xT[n][:]
// Q,K -> [bh][l][32] with vectorized uint2 epilogue stores (4 consecutive d
// per lane, C-layout gives 4 consecutive o per lane). V -> tiled
// [bh][kc64][d32][kk64] (scalar stores; layout required by attn A-frags).
// ---------------------------------------------------------------------------
__global__ __launch_bounds__(256) void qkv_kernel(const unsigned short* __restrict__ wq,
        const unsigned short* __restrict__ xT, const float* __restrict__ bias,
        unsigned short* __restrict__ qh, unsigned short* __restrict__ kh,
        unsigned short* __restrict__ vh) {
    int bid = blockIdx.x;
    int ot = bid % 6;
    int nt = bid / 6;                 // 0..127
    int lane = threadIdx.x & 63;
    int wv = threadIdx.x >> 6;
    int m16 = lane & 15, quad = lane >> 4;
    int o0 = ot * 64 + wv * 16;
    int n0 = nt * 128;

    bf16x8 af[4];
    #pragma unroll
    for (int ks = 0; ks < 4; ks++)
        af[ks] = *(const bf16x8*)(wq + (size_t)(o0 + m16) * Cdim + ks * 32 + quad * 8);
    float bs[4];
    #pragma unroll
    for (int r = 0; r < 4; r++) bs[r] = bias[o0 + quad * 4 + r];
    int oq = o0 + quad * 4;

    for (int lt2 = 0; lt2 < 8; lt2++) {
        int n = n0 + lt2 * 16 + m16;
        f32x4 acc = {0.f, 0.f, 0.f, 0.f};
        #pragma unroll
        for (int ks = 0; ks < 4; ks++) {
            bf16x8 bx = *(const bf16x8*)(xT + (size_t)n * Cdim + ks * 32 + quad * 8);
            acc = MFMA16(af[ks], bx, acc);
        }
        int b = n >> 11, l = n & (Lseq - 1);
        if (ot < 2) {            // Q (scaled): one uint2 store, d0 4-aligned
            int h = oq >> 5, d0 = oq & 31;
            uint2 u;
            u.x = pack_bf16((acc[0] + bs[0]) * QSCALE, (acc[1] + bs[1]) * QSCALE);
            u.y = pack_bf16((acc[2] + bs[2]) * QSCALE, (acc[3] + bs[3]) * QSCALE);
            *(uint2*)(qh + ((size_t)(b * NH + h) * Lseq + l) * HD + d0) = u;
        } else if (ot < 4) {     // K
            int o = oq - Cdim, h = o >> 5, d0 = o & 31;
            uint2 u;
            u.x = pack_bf16(acc[0] + bs[0], acc[1] + bs[1]);
            u.y = pack_bf16(acc[2] + bs[2], acc[3] + bs[3]);
            *(uint2*)(kh + ((size_t)(b * NH + h) * Lseq + l) * HD + d0) = u;
        } else {                 // V tiled: [bh][kc][d][kk]
            #pragma unroll
            for (int r = 0; r < 4; r++) {
                int o = oq + r - 2 * Cdim, h = o >> 5, d = o & 31;
                int kc = l >> 6, kk = l & 63;
                vh[(((size_t)(b * NH + h) * 32 + kc) * HD + d) * 64 + kk] =
                    f2bf(acc[r] + bs[r]);
            }
        }
    }
}

// ---------------------------------------------------------------------------
// Kernel 2: MFMA flash attention, key-split across waves, ZERO P data
// movement. Trick: PV contracts over keys in permuted order
//   kappa(8q+j) = 4q+j (j<4), 16+4q+(j-4) (j>=4)
// which makes the post-exp packed registers [u00,u01,u10,u11] directly a
// valid P B-fragment (B[k=8q+j][n=query]); V's A-frag in the SAME kappa
// order is two b64 loads per d-row from the tiled [bh][kc][d][kk] layout.
// MFMA is insensitive to the k-summation order => result unchanged.
// No LDS in hot loop; LDS only for the final cross-wave partial-O/l reduce
// (packed bf16, one barrier).
// ---------------------------------------------------------------------------
__global__ __launch_bounds__(256) void attn_kernel(
        const unsigned short* __restrict__ qh, const unsigned short* __restrict__ kh,
        const unsigned short* __restrict__ vh, unsigned short* __restrict__ attnb) {
    // red_o: [4][64] rows x 18 uints (slots 0..15 = packed d-pairs, 2 pad) = 18432 B
    // red_l: [4][64] float @ 18432                                  total 19456 B
    __shared__ __attribute__((aligned(16))) char smem[19456];

    int bid = blockIdx.x;
    int xcd  = bid & 7;                 // same bh -> same XCD (K/V L2 residency)
    int rest = bid >> 3;
    int qt = rest & 31;
    int bh = xcd + 8 * (rest >> 5);

    int lane = threadIdx.x & 63;
    int wv   = threadIdx.x >> 6;
    int m16  = lane & 15;
    int quad = lane >> 4;
    int l0 = qt * 64;

    // Q B-frags for the 4 q-subtiles
    bf16x8 qf[4];
    #pragma unroll
    for (int qs = 0; qs < 4; qs++)
        qf[qs] = *(const bf16x8*)(qh + ((size_t)bh * Lseq + l0 + qs * 16 + m16) * HD + quad * 8);

    f32x4 oacc[4][2];
    #pragma unroll
    for (int qs = 0; qs < 4; qs++) {
        oacc[qs][0] = f32x4{0.f, 0.f, 0.f, 0.f};
        oacc[qs][1] = f32x4{0.f, 0.f, 0.f, 0.f};
    }
    float lsum[4] = {0.f, 0.f, 0.f, 0.f};
    f32x4 zero = {0.f, 0.f, 0.f, 0.f};

    const unsigned short* kb = kh + (size_t)bh * Lseq * HD + m16 * HD + quad * 8;
    const unsigned short* vb = vh + (size_t)bh * 32 * HD * 64;

    for (int it = 0; it < 8; it++) {
        int k0 = wv * 512 + it * 64;
        // K A-frags: A[m=key][k=d]
        bf16x8 kf[4];
        #pragma unroll
        for (int t = 0; t < 4; t++)
            kf[t] = *(const bf16x8*)(kb + (size_t)(k0 + 16 * t) * HD);

        // V A-frags in kappa order: lane (quad, m16=d-row) takes keys
        // {4q..4q+3, 16+4q..+3} (key-lo group) and +32 (key-hi group).
        const unsigned short* vch = vb + (size_t)(k0 >> 6) * (HD * 64);
        const unsigned short* vrl = vch + m16 * 64 + 4 * quad;          // d = m16
        const unsigned short* vrh = vch + (16 + m16) * 64 + 4 * quad;   // d = 16+m16
        bf16x4 v0 = *(const bf16x4*)(vrl);
        bf16x4 v1 = *(const bf16x4*)(vrl + 16);
        bf16x4 v2 = *(const bf16x4*)(vrl + 32);
        bf16x4 v3 = *(const bf16x4*)(vrl + 48);
        bf16x4 w0 = *(const bf16x4*)(vrh);
        bf16x4 w1 = *(const bf16x4*)(vrh + 16);
        bf16x4 w2 = *(const bf16x4*)(vrh + 32);
        bf16x4 w3 = *(const bf16x4*)(vrh + 48);
        bf16x8 vfLL = __builtin_shufflevector(v0, v1, 0, 1, 2, 3, 4, 5, 6, 7);
        bf16x8 vfLH = __builtin_shufflevector(v2, v3, 0, 1, 2, 3, 4, 5, 6, 7);
        bf16x8 vfHL = __builtin_shufflevector(w0, w1, 0, 1, 2, 3, 4, 5, 6, 7);
        bf16x8 vfHH = __builtin_shufflevector(w2, w3, 0, 1, 2, 3, 4, 5, 6, 7);

        #pragma unroll
        for (int qs = 0; qs < 4; qs++) {
            // S: lane (quad,m16) reg r = key 16t+4*quad+r, query m16
            f32x4 s0 = MFMA16(kf[0], qf[qs], zero);
            f32x4 s1 = MFMA16(kf[1], qf[qs], zero);
            f32x4 s2 = MFMA16(kf[2], qf[qs], zero);
            f32x4 s3 = MFMA16(kf[3], qf[qs], zero);
            float p00 = fexp2(s0[0]), p01 = fexp2(s0[1]), p02 = fexp2(s0[2]), p03 = fexp2(s0[3]);
            float p10 = fexp2(s1[0]), p11 = fexp2(s1[1]), p12 = fexp2(s1[2]), p13 = fexp2(s1[3]);
            float p20 = fexp2(s2[0]), p21 = fexp2(s2[1]), p22 = fexp2(s2[2]), p23 = fexp2(s2[3]);
            float p30 = fexp2(s3[0]), p31 = fexp2(s3[1]), p32 = fexp2(s3[2]), p33 = fexp2(s3[3]);
            lsum[qs] += ((p00 + p01) + (p02 + p03)) + ((p10 + p11) + (p12 + p13)) +
                        ((p20 + p21) + (p22 + p23)) + ((p30 + p31) + (p32 + p33));
            // packed regs ARE the B-frag in kappa order — no data movement
            u32x4 lo = {pack_bf16_rtz(p00, p01), pack_bf16_rtz(p02, p03),
                        pack_bf16_rtz(p10, p11), pack_bf16_rtz(p12, p13)};
            u32x4 hi = {pack_bf16_rtz(p20, p21), pack_bf16_rtz(p22, p23),
                        pack_bf16_rtz(p30, p31), pack_bf16_rtz(p32, p33)};
            bf16x8 pfL = __builtin_bit_cast(bf16x8, lo);
            bf16x8 pfH = __builtin_bit_cast(bf16x8, hi);
            oacc[qs][0] = MFMA16(vfLL, pfL, oacc[qs][0]);
            oacc[qs][1] = MFMA16(vfHL, pfL, oacc[qs][1]);
            oacc[qs][0] = MFMA16(vfLH, pfH, oacc[qs][0]);
            oacc[qs][1] = MFMA16(vfHH, pfH, oacc[qs][1]);
        }
    }

    // per-wave rowsum for query m16 of each subtile (reduce over quads)
    #pragma unroll
    for (int qs = 0; qs < 4; qs++) {
        float v = lsum[qs];
        v += __shfl_xor(v, 16);
        v += __shfl_xor(v, 32);
        lsum[qs] = v;
    }

    // cross-wave reduction: packed-bf16 partials, one barrier
    unsigned* red_o = (unsigned*)smem;               // [4*64 rows][18]
    float* red_l = (float*)(smem + 18432);
    #pragma unroll
    for (int qs = 0; qs < 4; qs++) {
        int row = qs * 16 + m16;
        unsigned* rw = red_o + (size_t)(wv * 64 + row) * 18;
        *(uint2*)(rw + 2 * quad) =
            make_uint2(pack_bf16_rtz(oacc[qs][0][0], oacc[qs][0][1]),
                       pack_bf16_rtz(oacc[qs][0][2], oacc[qs][0][3]));
        *(uint2*)(rw + 8 + 2 * quad) =
            make_uint2(pack_bf16_rtz(oacc[qs][1][0], oacc[qs][1][1]),
                       pack_bf16_rtz(oacc[qs][1][2], oacc[qs][1][3]));
        if (quad == 0) red_l[wv * 64 + row] = lsum[qs];
    }
    __syncthreads();

    // combine: thread -> (q = t>>2, d0 = (t&3)*8); slot s holds d=(2s,2s+1)
    int q = threadIdx.x >> 2;
    int s4 = (threadIdx.x & 3) * 4;
    float a8[8] = {0.f, 0.f, 0.f, 0.f, 0.f, 0.f, 0.f, 0.f};
    float lt = 0.f;
    #pragma unroll
    for (int w = 0; w < 4; w++) {
        const unsigned* rr = red_o + (size_t)(w * 64 + q) * 18 + s4;
        uint2 ua = *(const uint2*)(rr);
        uint2 ub = *(const uint2*)(rr + 2);
        a8[0] += bf_lo(ua.x); a8[1] += bf_hi(ua.x);
        a8[2] += bf_lo(ua.y); a8[3] += bf_hi(ua.y);
        a8[4] += bf_lo(ub.x); a8[5] += bf_hi(ub.x);
        a8[6] += bf_lo(ub.y); a8[7] += bf_hi(ub.y);
        lt += red_l[w * 64 + q];
    }
    float inv = 1.0f / lt;
    int b = bh >> 2, h = bh & 3;
    int d0 = (threadIdx.x & 3) * 8;
    unsigned short* ob = attnb + ((size_t)b * Lseq + l0 + q) * Cdim + h * HD + d0;
    uint4 u;
    u.x = pack_bf16(a8[0] * inv, a8[1] * inv);
    u.y = pack_bf16(a8[2] * inv, a8[3] * inv);
    u.z = pack_bf16(a8[4] * inv, a8[5] * inv);
    u.w = pack_bf16(a8[6] * inv, a8[7] * inv);
    *(uint4*)ob = u;
}

// ---------------------------------------------------------------------------
// Kernel 3: output projection as bf16 MFMA GEMM + bias + residual (fp32 out).
// ---------------------------------------------------------------------------
__global__ __launch_bounds__(256) void proj_kernel(const unsigned short* __restrict__ wp,
        const unsigned short* __restrict__ attnb, const float* __restrict__ bias,
        const float* __restrict__ x, float* __restrict__ out) {
    int bid = blockIdx.x;
    int ot = bid & 1;
    int nt = bid >> 1;                // 0..255
    int lane = threadIdx.x & 63;
    int wv = threadIdx.x >> 6;
    int m16 = lane & 15, quad = lane >> 4;
    int o0 = ot * 64 + wv * 16;
    int n0 = nt * 64;

    bf16x8 af[4];
    #pragma unroll
    for (int ks = 0; ks < 4; ks++)
        af[ks] = *(const bf16x8*)(wp + (size_t)(o0 + m16) * Cdim + ks * 32 + quad * 8);
    float bs[4];
    #pragma unroll
    for (int r = 0; r < 4; r++) bs[r] = bias[o0 + quad * 4 + r];
    int oq = o0 + quad * 4;

    for (int lt2 = 0; lt2 < 4; lt2++) {
        int n = n0 + lt2 * 16 + m16;
        f32x4 acc = {0.f, 0.f, 0.f, 0.f};
        #pragma unroll
        for (int ks = 0; ks < 4; ks++) {
            bf16x8 bx = *(const bf16x8*)(attnb + (size_t)n * Cdim + ks * 32 + quad * 8);
            acc = MFMA16(af[ks], bx, acc);
        }
        int b = n >> 11, l = n & (Lseq - 1);
        #pragma unroll
        for (int r = 0; r < 4; r++) {
            size_t xi = ((size_t)b * Cdim + oq + r) * Lseq + l;
            out[xi] = acc[r] + bs[r] + x[xi];
        }
    }
}

extern "C" void kernel_launch(void* const* d_in, const int* in_sizes, int n_in,
                              void* d_out, int out_size, void* d_ws, size_t ws_size,
                              hipStream_t stream) {
    const float* x      = (const float*)d_in[0];
    const float* w_qkv  = (const float*)d_in[1];
    const float* b_qkv  = (const float*)d_in[2];
    const float* w_proj = (const float*)d_in[3];
    const float* b_proj = (const float*)d_in[4];
    float* out = (float*)d_out;

    // ws (ushorts): qh 2M | kh 2M | vh 2M | attnb 2M | xT 2M | wqb 49152 | wpb 16384
    const size_t E = (size_t)BH * Lseq * HD;   // 2M elems = 4 MB
    unsigned short* qh    = (unsigned short*)d_ws;
    unsigned short* kh    = qh + E;
    unsigned short* vh    = kh + E;
    unsigned short* attnb = vh + E;
    unsigned short* xT    = attnb + E;
    unsigned short* wqb   = xT + E;
    unsigned short* wpb   = wqb + 3 * Cdim * Cdim;

    prep_kernel<<<dim3(280), dim3(256), 0, stream>>>(x, w_qkv, w_proj, xT, wqb, wpb);
    qkv_kernel<<<dim3(768), dim3(256), 0, stream>>>(wqb, xT, b_qkv, qh, kh, vh);
    attn_kernel<<<dim3(BH * 32), dim3(256), 0, stream>>>(qh, kh, vh, attnb);
    proj_kernel<<<dim3(512), dim3(256), 0, stream>>>(wpb, attnb, b_proj, x, out);
}

// Round 8
// 131.175 us; speedup vs baseline: 2.0748x; 1.0609x over previous
//
#include <hip/hip_runtime.h>

// Problem constants: B=8, C=128, L=2048, H=4, D=32
#define Bsz 8
#define Cdim 128
#define Lseq 2048
#define NH 4
#define HD 32
#define BH 32
// 1/sqrt(D) * log2(e): scores feed v_exp_f32 (2^x) directly
#define QSCALE (0.17677669529663687f * 1.4426950408889634f)

typedef __bf16 bf16x8 __attribute__((ext_vector_type(8)));
typedef __bf16 bf16x4 __attribute__((ext_vector_type(4)));
typedef float f32x4 __attribute__((ext_vector_type(4)));
typedef unsigned u32x4 __attribute__((ext_vector_type(4)));

__device__ __forceinline__ float fexp2(float x) {
#if __has_builtin(__builtin_amdgcn_exp2f)
    return __builtin_amdgcn_exp2f(x);
#else
    return __expf(x * 0.6931471805599453f);
#endif
}

__device__ __forceinline__ unsigned short f2bf(float f) {   // RNE
    unsigned u = __builtin_bit_cast(unsigned, f);
    u += 0x7FFFu + ((u >> 16) & 1u);
    return (unsigned short)(u >> 16);
}

__device__ __forceinline__ unsigned pack_bf16(float a, float b) {  // RNE pair
    return (unsigned)f2bf(a) | ((unsigned)f2bf(b) << 16);
}

// RTZ pack of two f32 -> packed bf16x2, single v_perm_b32.
__device__ __forceinline__ unsigned pack_bf16_rtz(float a, float b) {
    return __builtin_amdgcn_perm(__builtin_bit_cast(unsigned, b),
                                 __builtin_bit_cast(unsigned, a), 0x07060302u);
}

__device__ __forceinline__ float bf_lo(unsigned u) {
    return __builtin_bit_cast(float, u << 16);
}
__device__ __forceinline__ float bf_hi(unsigned u) {
    return __builtin_bit_cast(float, u & 0xFFFF0000u);
}

#define MFMA16(A, B, C) __builtin_amdgcn_mfma_f32_16x16x32_bf16((A), (B), (C), 0, 0, 0)

// ---------------------------------------------------------------------------
// Kernel 1: QKV projection, fully fused: stages its own x-tile (fp32->bf16
// transpose via LDS) and converts w_qkv fp32->bf16 fragments in registers.
// Block = one (b, 64-l tile); computes ALL 384 outputs for those 64 l.
// Wave wv owns 96 o-rows (6 subtiles). Q,K -> [bh][l][32] (uint2 stores),
// V -> tiled [bh][kc64][d32][kk64].
// ---------------------------------------------------------------------------
__global__ __launch_bounds__(256) void qkv_kernel(const float* __restrict__ x,
        const float* __restrict__ w, const float* __restrict__ bias,
        unsigned short* __restrict__ qh, unsigned short* __restrict__ kh,
        unsigned short* __restrict__ vh) {
    __shared__ __attribute__((aligned(16))) unsigned short T[64][132];
    int bid = blockIdx.x;
    int b  = bid >> 5;
    int l0 = (bid & 31) * 64;
    int t = threadIdx.x;
    int lane = t & 63, wv = t >> 6;
    int m16 = lane & 15, quad = lane >> 4;
    int o0w = wv * 96;

    // A-frags: A[m=o(m16)][k=c=ks*32+quad*8+j], converted from fp32 w
    bf16x8 af[6][4];
    #pragma unroll
    for (int os = 0; os < 6; os++) {
        const float* wr = w + (size_t)(o0w + os * 16 + m16) * Cdim;
        #pragma unroll
        for (int ks = 0; ks < 4; ks++) {
            const float* p = wr + ks * 32 + quad * 8;
            float4 f0 = *(const float4*)p;
            float4 f1 = *(const float4*)(p + 4);
            u32x4 u = {pack_bf16(f0.x, f0.y), pack_bf16(f0.z, f0.w),
                       pack_bf16(f1.x, f1.y), pack_bf16(f1.z, f1.w)};
            af[os][ks] = __builtin_bit_cast(bf16x8, u);
        }
    }

    // stage x tile: T[l][c] = bf16(x[b][c][l0+l]) — loads coalesced over l,
    // paired-c packed b32 LDS writes (2-way conflicts only = free)
    {
        int l = t & 63, cg = t >> 6;
        const float* xb = x + (size_t)b * Cdim * Lseq + l0 + l;
        #pragma unroll
        for (int i = 0; i < 16; i++) {
            int c = cg * 32 + 2 * i;
            float f0 = xb[(size_t)c * Lseq];
            float f1 = xb[(size_t)(c + 1) * Lseq];
            *(unsigned*)&T[l][c] = pack_bf16(f0, f1);
        }
    }

    float bs[6][4];
    #pragma unroll
    for (int os = 0; os < 6; os++)
        #pragma unroll
        for (int r = 0; r < 4; r++)
            bs[os][r] = bias[o0w + os * 16 + quad * 4 + r];

    __syncthreads();

    #pragma unroll
    for (int ns = 0; ns < 4; ns++) {
        bf16x8 bx[4];   // B[k=c][n=l(m16)]
        #pragma unroll
        for (int ks = 0; ks < 4; ks++)
            bx[ks] = *(const bf16x8*)(&T[ns * 16 + m16][ks * 32 + quad * 8]);
        int l = l0 + ns * 16 + m16;
        int kc = l >> 6, kk = l & 63;
        #pragma unroll
        for (int os = 0; os < 6; os++) {
            f32x4 acc = {0.f, 0.f, 0.f, 0.f};
            #pragma unroll
            for (int ks = 0; ks < 4; ks++) acc = MFMA16(af[os][ks], bx[ks], acc);
            int o0s = o0w + os * 16 + quad * 4;   // 4 consecutive o per lane
            if (o0s < Cdim) {            // Q (scaled)
                int h = o0s >> 5, d0 = o0s & 31;
                uint2 u;
                u.x = pack_bf16((acc[0] + bs[os][0]) * QSCALE, (acc[1] + bs[os][1]) * QSCALE);
                u.y = pack_bf16((acc[2] + bs[os][2]) * QSCALE, (acc[3] + bs[os][3]) * QSCALE);
                *(uint2*)(qh + ((size_t)(b * NH + h) * Lseq + l) * HD + d0) = u;
            } else if (o0s < 2 * Cdim) { // K
                int o = o0s - Cdim, h = o >> 5, d0 = o & 31;
                uint2 u;
                u.x = pack_bf16(acc[0] + bs[os][0], acc[1] + bs[os][1]);
                u.y = pack_bf16(acc[2] + bs[os][2], acc[3] + bs[os][3]);
                *(uint2*)(kh + ((size_t)(b * NH + h) * Lseq + l) * HD + d0) = u;
            } else {                     // V tiled [bh][kc][d][kk]
                #pragma unroll
                for (int r = 0; r < 4; r++) {
                    int o = o0s + r - 2 * Cdim, h = o >> 5, d = o & 31;
                    vh[(((size_t)(b * NH + h) * 32 + kc) * HD + d) * 64 + kk] =
                        f2bf(acc[r] + bs[os][r]);
                }
            }
        }
    }
}

// ---------------------------------------------------------------------------
// Kernel 2: MFMA flash attention: key-split waves, kappa-packed P (zero P
// data movement), explicit next-iteration K/V prefetch, rowsums via ones-A
// MFMA (VALU -> idle MFMA pipe). LDS only for final cross-wave reduce.
// ---------------------------------------------------------------------------
__global__ __launch_bounds__(256) void attn_kernel(
        const unsigned short* __restrict__ qh, const unsigned short* __restrict__ kh,
        const unsigned short* __restrict__ vh, unsigned short* __restrict__ attnb) {
    // red_o: [4][64] rows x 18 uints = 18432 B; red_l: [4][64] float @18432
    __shared__ __attribute__((aligned(16))) char smem[19456];

    int bid = blockIdx.x;
    int xcd  = bid & 7;                 // same bh -> same XCD (K/V L2 residency)
    int rest = bid >> 3;
    int qt = rest & 31;
    int bh = xcd + 8 * (rest >> 5);

    int lane = threadIdx.x & 63;
    int wv   = threadIdx.x >> 6;
    int m16  = lane & 15;
    int quad = lane >> 4;
    int l0 = qt * 64;

    bf16x8 qf[4];
    #pragma unroll
    for (int qs = 0; qs < 4; qs++)
        qf[qs] = *(const bf16x8*)(qh + ((size_t)bh * Lseq + l0 + qs * 16 + m16) * HD + quad * 8);

    bf16x8 ones;
    #pragma unroll
    for (int i = 0; i < 8; i++) ones[i] = (__bf16)1.0f;

    f32x4 oacc[4][2];
    f32x4 lacc[4];
    #pragma unroll
    for (int qs = 0; qs < 4; qs++) {
        oacc[qs][0] = f32x4{0.f, 0.f, 0.f, 0.f};
        oacc[qs][1] = f32x4{0.f, 0.f, 0.f, 0.f};
        lacc[qs]    = f32x4{0.f, 0.f, 0.f, 0.f};
    }
    f32x4 zero = {0.f, 0.f, 0.f, 0.f};

    const unsigned short* kb = kh + (size_t)bh * Lseq * HD + m16 * HD + quad * 8;
    const unsigned short* vb = vh + (size_t)bh * 32 * HD * 64;

    // ---- load helpers (inlined twice) ----
    bf16x8 kf[4], vf[4], kfN[4], vfN[4];
    {
        int k0 = wv * 512;
        #pragma unroll
        for (int t = 0; t < 4; t++)
            kf[t] = *(const bf16x8*)(kb + (size_t)(k0 + 16 * t) * HD);
        const unsigned short* vch = vb + (size_t)(k0 >> 6) * (HD * 64);
        const unsigned short* vrl = vch + m16 * 64 + 4 * quad;
        const unsigned short* vrh = vch + (16 + m16) * 64 + 4 * quad;
        bf16x4 a0 = *(const bf16x4*)(vrl),      a1 = *(const bf16x4*)(vrl + 16);
        bf16x4 a2 = *(const bf16x4*)(vrl + 32), a3 = *(const bf16x4*)(vrl + 48);
        bf16x4 b0 = *(const bf16x4*)(vrh),      b1 = *(const bf16x4*)(vrh + 16);
        bf16x4 b2 = *(const bf16x4*)(vrh + 32), b3 = *(const bf16x4*)(vrh + 48);
        vf[0] = __builtin_shufflevector(a0, a1, 0, 1, 2, 3, 4, 5, 6, 7);
        vf[1] = __builtin_shufflevector(b0, b1, 0, 1, 2, 3, 4, 5, 6, 7);
        vf[2] = __builtin_shufflevector(a2, a3, 0, 1, 2, 3, 4, 5, 6, 7);
        vf[3] = __builtin_shufflevector(b2, b3, 0, 1, 2, 3, 4, 5, 6, 7);
    }

    for (int it = 0; it < 8; it++) {
        // prefetch next chunk's K/V (last iter: reload current, harmless)
        int nx = it < 7 ? it + 1 : 7;
        {
            int k0 = wv * 512 + nx * 64;
            #pragma unroll
            for (int t = 0; t < 4; t++)
                kfN[t] = *(const bf16x8*)(kb + (size_t)(k0 + 16 * t) * HD);
            const unsigned short* vch = vb + (size_t)(k0 >> 6) * (HD * 64);
            const unsigned short* vrl = vch + m16 * 64 + 4 * quad;
            const unsigned short* vrh = vch + (16 + m16) * 64 + 4 * quad;
            bf16x4 a0 = *(const bf16x4*)(vrl),      a1 = *(const bf16x4*)(vrl + 16);
            bf16x4 a2 = *(const bf16x4*)(vrl + 32), a3 = *(const bf16x4*)(vrl + 48);
            bf16x4 b0 = *(const bf16x4*)(vrh),      b1 = *(const bf16x4*)(vrh + 16);
            bf16x4 b2 = *(const bf16x4*)(vrh + 32), b3 = *(const bf16x4*)(vrh + 48);
            vfN[0] = __builtin_shufflevector(a0, a1, 0, 1, 2, 3, 4, 5, 6, 7);
            vfN[1] = __builtin_shufflevector(b0, b1, 0, 1, 2, 3, 4, 5, 6, 7);
            vfN[2] = __builtin_shufflevector(a2, a3, 0, 1, 2, 3, 4, 5, 6, 7);
            vfN[3] = __builtin_shufflevector(b2, b3, 0, 1, 2, 3, 4, 5, 6, 7);
        }

        #pragma unroll
        for (int qs = 0; qs < 4; qs++) {
            f32x4 s0 = MFMA16(kf[0], qf[qs], zero);
            f32x4 s1 = MFMA16(kf[1], qf[qs], zero);
            f32x4 s2 = MFMA16(kf[2], qf[qs], zero);
            f32x4 s3 = MFMA16(kf[3], qf[qs], zero);
            float p00 = fexp2(s0[0]), p01 = fexp2(s0[1]), p02 = fexp2(s0[2]), p03 = fexp2(s0[3]);
            float p10 = fexp2(s1[0]), p11 = fexp2(s1[1]), p12 = fexp2(s1[2]), p13 = fexp2(s1[3]);
            float p20 = fexp2(s2[0]), p21 = fexp2(s2[1]), p22 = fexp2(s2[2]), p23 = fexp2(s2[3]);
            float p30 = fexp2(s3[0]), p31 = fexp2(s3[1]), p32 = fexp2(s3[2]), p33 = fexp2(s3[3]);
            // packed regs ARE the P B-frag in kappa key-order
            u32x4 lo = {pack_bf16_rtz(p00, p01), pack_bf16_rtz(p02, p03),
                        pack_bf16_rtz(p10, p11), pack_bf16_rtz(p12, p13)};
            u32x4 hi = {pack_bf16_rtz(p20, p21), pack_bf16_rtz(p22, p23),
                        pack_bf16_rtz(p30, p31), pack_bf16_rtz(p32, p33)};
            bf16x8 pfL = __builtin_bit_cast(bf16x8, lo);
            bf16x8 pfH = __builtin_bit_cast(bf16x8, hi);
            oacc[qs][0] = MFMA16(vf[0], pfL, oacc[qs][0]);
            oacc[qs][1] = MFMA16(vf[1], pfL, oacc[qs][1]);
            lacc[qs]    = MFMA16(ones,  pfL, lacc[qs]);
            oacc[qs][0] = MFMA16(vf[2], pfH, oacc[qs][0]);
            oacc[qs][1] = MFMA16(vf[3], pfH, oacc[qs][1]);
            lacc[qs]    = MFMA16(ones,  pfH, lacc[qs]);
        }
        #pragma unroll
        for (int t = 0; t < 4; t++) { kf[t] = kfN[t]; vf[t] = vfN[t]; }
    }

    // cross-wave reduction: packed-bf16 partials, one barrier
    unsigned* red_o = (unsigned*)smem;               // [4*64 rows][18]
    float* red_l = (float*)(smem + 18432);
    #pragma unroll
    for (int qs = 0; qs < 4; qs++) {
        int row = qs * 16 + m16;
        unsigned* rw = red_o + (size_t)(wv * 64 + row) * 18;
        *(uint2*)(rw + 2 * quad) =
            make_uint2(pack_bf16_rtz(oacc[qs][0][0], oacc[qs][0][1]),
                       pack_bf16_rtz(oacc[qs][0][2], oacc[qs][0][3]));
        *(uint2*)(rw + 8 + 2 * quad) =
            make_uint2(pack_bf16_rtz(oacc[qs][1][0], oacc[qs][1][1]),
                       pack_bf16_rtz(oacc[qs][1][2], oacc[qs][1][3]));
        if (quad == 0) red_l[wv * 64 + row] = lacc[qs][0];  // rowsum (replicated regs)
    }
    __syncthreads();

    int q = threadIdx.x >> 2;
    int s4 = (threadIdx.x & 3) * 4;
    float a8[8] = {0.f, 0.f, 0.f, 0.f, 0.f, 0.f, 0.f, 0.f};
    float lt = 0.f;
    #pragma unroll
    for (int w = 0; w < 4; w++) {
        const unsigned* rr = red_o + (size_t)(w * 64 + q) * 18 + s4;
        uint2 ua = *(const uint2*)(rr);
        uint2 ub = *(const uint2*)(rr + 2);
        a8[0] += bf_lo(ua.x); a8[1] += bf_hi(ua.x);
        a8[2] += bf_lo(ua.y); a8[3] += bf_hi(ua.y);
        a8[4] += bf_lo(ub.x); a8[5] += bf_hi(ub.x);
        a8[6] += bf_lo(ub.y); a8[7] += bf_hi(ub.y);
        lt += red_l[w * 64 + q];
    }
    float inv = 1.0f / lt;
    int b = bh >> 2, h = bh & 3;
    int d0 = (threadIdx.x & 3) * 8;
    unsigned short* ob = attnb + ((size_t)b * Lseq + l0 + q) * Cdim + h * HD + d0;
    uint4 u;
    u.x = pack_bf16(a8[0] * inv, a8[1] * inv);
    u.y = pack_bf16(a8[2] * inv, a8[3] * inv);
    u.z = pack_bf16(a8[4] * inv, a8[5] * inv);
    u.w = pack_bf16(a8[6] * inv, a8[7] * inv);
    *(uint4*)ob = u;
}

// ---------------------------------------------------------------------------
// Kernel 3: output projection (w_proj fp32 -> bf16 frags in-reg) + bias +
// residual, fp32 out. B = attnb [b][l][128] bf16 (c-contiguous).
// ---------------------------------------------------------------------------
__global__ __launch_bounds__(256) void proj_kernel(const float* __restrict__ wp,
        const unsigned short* __restrict__ attnb, const float* __restrict__ bias,
        const float* __restrict__ x, float* __restrict__ out) {
    int bid = blockIdx.x;
    int ot = bid & 1;
    int nt = bid >> 1;                // 0..255
    int lane = threadIdx.x & 63;
    int wv = threadIdx.x >> 6;
    int m16 = lane & 15, quad = lane >> 4;
    int o0 = ot * 64 + wv * 16;
    int n0 = nt * 64;

    bf16x8 af[4];
    #pragma unroll
    for (int ks = 0; ks < 4; ks++) {
        const float* p = wp + (size_t)(o0 + m16) * Cdim + ks * 32 + quad * 8;
        float4 f0 = *(const float4*)p;
        float4 f1 = *(const float4*)(p + 4);
        u32x4 u = {pack_bf16(f0.x, f0.y), pack_bf16(f0.z, f0.w),
                   pack_bf16(f1.x, f1.y), pack_bf16(f1.z, f1.w)};
        af[ks] = __builtin_bit_cast(bf16x8, u);
    }
    float bs[4];
    #pragma unroll
    for (int r = 0; r < 4; r++) bs[r] = bias[o0 + quad * 4 + r];
    int oq = o0 + quad * 4;

    for (int lt2 = 0; lt2 < 4; lt2++) {
        int n = n0 + lt2 * 16 + m16;
        f32x4 acc = {0.f, 0.f, 0.f, 0.f};
        #pragma unroll
        for (int ks = 0; ks < 4; ks++) {
            bf16x8 bx = *(const bf16x8*)(attnb + (size_t)n * Cdim + ks * 32 + quad * 8);
            acc = MFMA16(af[ks], bx, acc);
        }
        int b = n >> 11, l = n & (Lseq - 1);
        #pragma unroll
        for (int r = 0; r < 4; r++) {
            size_t xi = ((size_t)b * Cdim + oq + r) * Lseq + l;
            out[xi] = acc[r] + bs[r] + x[xi];
        }
    }
}

extern "C" void kernel_launch(void* const* d_in, const int* in_sizes, int n_in,
                              void* d_out, int out_size, void* d_ws, size_t ws_size,
                              hipStream_t stream) {
    const float* x      = (const float*)d_in[0];
    const float* w_qkv  = (const float*)d_in[1];
    const float* b_qkv  = (const float*)d_in[2];
    const float* w_proj = (const float*)d_in[3];
    const float* b_proj = (const float*)d_in[4];
    float* out = (float*)d_out;

    // ws (ushorts): qh 2M | kh 2M | vh 2M | attnb 2M   (16 MB total)
    const size_t E = (size_t)BH * Lseq * HD;   // 2M elems = 4 MB
    unsigned short* qh    = (unsigned short*)d_ws;
    unsigned short* kh    = qh + E;
    unsigned short* vh    = kh + E;
    unsigned short* attnb = vh + E;

    qkv_kernel<<<dim3(256), dim3(256), 0, stream>>>(x, w_qkv, b_qkv, qh, kh, vh);
    attn_kernel<<<dim3(BH * 32), dim3(256), 0, stream>>>(qh, kh, vh, attnb);
    proj_kernel<<<dim3(512), dim3(256), 0, stream>>>(w_proj, attnb, b_proj, x, out);
}

// Round 9
// 121.163 us; speedup vs baseline: 2.2462x; 1.0826x over previous
//
#include <hip/hip_runtime.h>

// Problem constants: B=8, C=128, L=2048, H=4, D=32
#define Bsz 8
#define Cdim 128
#define Lseq 2048
#define NH 4
#define HD 32
#define BH 32
// 1/sqrt(D) * log2(e): scores feed v_exp_f32 (2^x) directly
#define QSCALE (0.17677669529663687f * 1.4426950408889634f)

typedef __bf16 bf16x8 __attribute__((ext_vector_type(8)));
typedef float f32x4 __attribute__((ext_vector_type(4)));
typedef unsigned u32x4 __attribute__((ext_vector_type(4)));

__device__ __forceinline__ float fexp2(float x) {
#if __has_builtin(__builtin_amdgcn_exp2f)
    return __builtin_amdgcn_exp2f(x);
#else
    return __expf(x * 0.6931471805599453f);
#endif
}

__device__ __forceinline__ unsigned short f2bf(float f) {   // RNE
    unsigned u = __builtin_bit_cast(unsigned, f);
    u += 0x7FFFu + ((u >> 16) & 1u);
    return (unsigned short)(u >> 16);
}

__device__ __forceinline__ unsigned pack_bf16(float a, float b) {  // RNE pair
    return (unsigned)f2bf(a) | ((unsigned)f2bf(b) << 16);
}

// RTZ pack of two f32 -> packed bf16x2, single v_perm_b32.
__device__ __forceinline__ unsigned pack_bf16_rtz(float a, float b) {
    return __builtin_amdgcn_perm(__builtin_bit_cast(unsigned, b),
                                 __builtin_bit_cast(unsigned, a), 0x07060302u);
}

__device__ __forceinline__ float bf_lo(unsigned u) {
    return __builtin_bit_cast(float, u << 16);
}
__device__ __forceinline__ float bf_hi(unsigned u) {
    return __builtin_bit_cast(float, u & 0xFFFF0000u);
}

#define MFMA16(A, B, C) __builtin_amdgcn_mfma_f32_16x16x32_bf16((A), (B), (C), 0, 0, 0)

// ---------------------------------------------------------------------------
// Kernel 1: QKV projection, fused staging. Grid 1536 = (b, lt, og): block
// computes 64 o-rows x 64 l. Wave = one 16-o subtile x 64 l (16 MFMAs).
// x-tile staged fp32->bf16 transpose via LDS (re-staged per og; L3 absorbs).
// Q,K -> [bh][l][32] (uint2 stores). V -> kappa-permuted tile
// [bh][kc64][d32][half32 + pos], pos = inv_kappa(key&31), so attn's PV
// B-frag key order matches V storage order (4 b128 loads, no shuffles).
// ---------------------------------------------------------------------------
__global__ __launch_bounds__(256) void qkv_kernel(const float* __restrict__ x,
        const float* __restrict__ w, const float* __restrict__ bias,
        unsigned short* __restrict__ qh, unsigned short* __restrict__ kh,
        unsigned short* __restrict__ vh) {
    __shared__ __attribute__((aligned(16))) unsigned short T[64][132];
    int bid = blockIdx.x;
    int og = bid % 6;                 // 6 o-groups of 64
    int lt = (bid / 6) & 31;          // 32 l-tiles of 64
    int b  = bid / 192;
    int l0 = lt * 64;
    int t = threadIdx.x;
    int lane = t & 63, wv = t >> 6;
    int m16 = lane & 15, quad = lane >> 4;
    int o0 = og * 64 + wv * 16;

    // A-frags: A[m=o(m16)][k=c], converted from fp32 w in registers
    bf16x8 af[4];
    #pragma unroll
    for (int ks = 0; ks < 4; ks++) {
        const float* p = w + (size_t)(o0 + m16) * Cdim + ks * 32 + quad * 8;
        float4 f0 = *(const float4*)p;
        float4 f1 = *(const float4*)(p + 4);
        u32x4 u = {pack_bf16(f0.x, f0.y), pack_bf16(f0.z, f0.w),
                   pack_bf16(f1.x, f1.y), pack_bf16(f1.z, f1.w)};
        af[ks] = __builtin_bit_cast(bf16x8, u);
    }
    float bs[4];
    #pragma unroll
    for (int r = 0; r < 4; r++) bs[r] = bias[o0 + quad * 4 + r];

    // stage x tile: T[l][c] = bf16(x[b][c][l0+l]); coalesced over l
    {
        int ll = t & 63, cg = t >> 6;
        const float* xb = x + (size_t)b * Cdim * Lseq + l0 + ll;
        #pragma unroll
        for (int i = 0; i < 16; i++) {
            int c = cg * 32 + 2 * i;
            float f0 = xb[(size_t)c * Lseq];
            float f1 = xb[(size_t)(c + 1) * Lseq];
            *(unsigned*)&T[ll][c] = pack_bf16(f0, f1);
        }
    }
    __syncthreads();

    int oq = o0 + quad * 4;
    #pragma unroll
    for (int ns = 0; ns < 4; ns++) {
        bf16x8 bx[4];   // B[k=c][n=l(m16)]
        #pragma unroll
        for (int ks = 0; ks < 4; ks++)
            bx[ks] = *(const bf16x8*)(&T[ns * 16 + m16][ks * 32 + quad * 8]);
        f32x4 acc = {0.f, 0.f, 0.f, 0.f};
        #pragma unroll
        for (int ks = 0; ks < 4; ks++) acc = MFMA16(af[ks], bx[ks], acc);
        int l = l0 + ns * 16 + m16;
        if (og < 2) {            // Q (scaled)
            int h = oq >> 5, d0 = oq & 31;
            uint2 u;
            u.x = pack_bf16((acc[0] + bs[0]) * QSCALE, (acc[1] + bs[1]) * QSCALE);
            u.y = pack_bf16((acc[2] + bs[2]) * QSCALE, (acc[3] + bs[3]) * QSCALE);
            *(uint2*)(qh + ((size_t)(b * NH + h) * Lseq + l) * HD + d0) = u;
        } else if (og < 4) {     // K
            int o = oq - Cdim, h = o >> 5, d0 = o & 31;
            uint2 u;
            u.x = pack_bf16(acc[0] + bs[0], acc[1] + bs[1]);
            u.y = pack_bf16(acc[2] + bs[2], acc[3] + bs[3]);
            *(uint2*)(kh + ((size_t)(b * NH + h) * Lseq + l) * HD + d0) = u;
        } else {                 // V kappa-permuted tiled store
            int kc = l >> 6, kk = l & 63;
            int half = kk >> 5, k32 = kk & 31;
            int q_, j_;
            if (k32 < 16) { q_ = k32 >> 2; j_ = k32 & 3; }
            else          { q_ = (k32 - 16) >> 2; j_ = 4 + ((k32 - 16) & 3); }
            int pos = half * 32 + q_ * 8 + j_;
            #pragma unroll
            for (int r = 0; r < 4; r++) {
                int o = oq + r - 2 * Cdim, h = o >> 5, d = o & 31;
                vh[(((size_t)(b * NH + h) * 32 + kc) * HD + d) * 64 + pos] =
                    f2bf(acc[r] + bs[r]);
            }
        }
    }
}

// ---------------------------------------------------------------------------
// Kernel 2: MFMA flash attention. Key-split waves, kappa-packed P (zero P
// movement), kappa-stored V (4 b128 loads, zero shuffles), manual 2x unroll
// with A/B register sets (no rotate copies), rowsums via ones-A MFMA.
// ---------------------------------------------------------------------------
__global__ __launch_bounds__(256) void attn_kernel(
        const unsigned short* __restrict__ qh, const unsigned short* __restrict__ kh,
        const unsigned short* __restrict__ vh, unsigned short* __restrict__ attnb) {
    // red_o: [4][64] rows x 18 uints = 18432 B; red_l: [4][64] float @18432
    __shared__ __attribute__((aligned(16))) char smem[19456];

    int bid = blockIdx.x;
    int xcd  = bid & 7;                 // same bh -> same XCD (K/V L2 residency)
    int rest = bid >> 3;
    int qt = rest & 31;
    int bh = xcd + 8 * (rest >> 5);

    int lane = threadIdx.x & 63;
    int wv   = threadIdx.x >> 6;
    int m16  = lane & 15;
    int quad = lane >> 4;
    int l0 = qt * 64;

    bf16x8 qf[4];
    #pragma unroll
    for (int qs = 0; qs < 4; qs++)
        qf[qs] = *(const bf16x8*)(qh + ((size_t)bh * Lseq + l0 + qs * 16 + m16) * HD + quad * 8);

    bf16x8 ones;
    #pragma unroll
    for (int i = 0; i < 8; i++) ones[i] = (__bf16)1.0f;

    f32x4 oacc[4][2];
    f32x4 lacc[4];
    #pragma unroll
    for (int qs = 0; qs < 4; qs++) {
        oacc[qs][0] = f32x4{0.f, 0.f, 0.f, 0.f};
        oacc[qs][1] = f32x4{0.f, 0.f, 0.f, 0.f};
        lacc[qs]    = f32x4{0.f, 0.f, 0.f, 0.f};
    }
    f32x4 zero = {0.f, 0.f, 0.f, 0.f};

    const unsigned short* kb = kh + (size_t)bh * Lseq * HD + m16 * HD + quad * 8;
    const unsigned short* vb = vh + (size_t)bh * 32 * HD * 64;
    int kbase = wv * 512;

    auto load_kv = [&](int chunk, bf16x8* kf, bf16x8* vf) {
        int k0 = kbase + chunk * 64;
        #pragma unroll
        for (int t = 0; t < 4; t++)
            kf[t] = *(const bf16x8*)(kb + (size_t)(k0 + 16 * t) * HD);
        const unsigned short* vch = vb + (size_t)(k0 >> 6) * (HD * 64);
        vf[0] = *(const bf16x8*)(vch + m16 * 64 + quad * 8);               // d0-15, lo
        vf[1] = *(const bf16x8*)(vch + (16 + m16) * 64 + quad * 8);        // d16-31, lo
        vf[2] = *(const bf16x8*)(vch + m16 * 64 + 32 + quad * 8);          // d0-15, hi
        vf[3] = *(const bf16x8*)(vch + (16 + m16) * 64 + 32 + quad * 8);   // d16-31, hi
    };

    auto compute = [&](const bf16x8* kf, const bf16x8* vf) {
        #pragma unroll
        for (int qs = 0; qs < 4; qs++) {
            f32x4 s0 = MFMA16(kf[0], qf[qs], zero);
            f32x4 s1 = MFMA16(kf[1], qf[qs], zero);
            f32x4 s2 = MFMA16(kf[2], qf[qs], zero);
            f32x4 s3 = MFMA16(kf[3], qf[qs], zero);
            float p00 = fexp2(s0[0]), p01 = fexp2(s0[1]), p02 = fexp2(s0[2]), p03 = fexp2(s0[3]);
            float p10 = fexp2(s1[0]), p11 = fexp2(s1[1]), p12 = fexp2(s1[2]), p13 = fexp2(s1[3]);
            float p20 = fexp2(s2[0]), p21 = fexp2(s2[1]), p22 = fexp2(s2[2]), p23 = fexp2(s2[3]);
            float p30 = fexp2(s3[0]), p31 = fexp2(s3[1]), p32 = fexp2(s3[2]), p33 = fexp2(s3[3]);
            // packed regs ARE the P B-frag in kappa key-order
            u32x4 lo = {pack_bf16_rtz(p00, p01), pack_bf16_rtz(p02, p03),
                        pack_bf16_rtz(p10, p11), pack_bf16_rtz(p12, p13)};
            u32x4 hi = {pack_bf16_rtz(p20, p21), pack_bf16_rtz(p22, p23),
                        pack_bf16_rtz(p30, p31), pack_bf16_rtz(p32, p33)};
            bf16x8 pfL = __builtin_bit_cast(bf16x8, lo);
            bf16x8 pfH = __builtin_bit_cast(bf16x8, hi);
            oacc[qs][0] = MFMA16(vf[0], pfL, oacc[qs][0]);
            oacc[qs][1] = MFMA16(vf[1], pfL, oacc[qs][1]);
            lacc[qs]    = MFMA16(ones,  pfL, lacc[qs]);
            oacc[qs][0] = MFMA16(vf[2], pfH, oacc[qs][0]);
            oacc[qs][1] = MFMA16(vf[3], pfH, oacc[qs][1]);
            lacc[qs]    = MFMA16(ones,  pfH, lacc[qs]);
        }
    };

    bf16x8 kA[4], vA[4], kB[4], vB[4];
    load_kv(0, kA, vA);
    load_kv(1, kB, vB);
    #pragma unroll
    for (int it = 0; it < 8; it += 2) {
        compute(kA, vA);                       // chunk it (B=it+1 in flight)
        load_kv(it + 2 < 8 ? it + 2 : 7, kA, vA);
        compute(kB, vB);                       // chunk it+1 (A=it+2 in flight)
        load_kv(it + 3 < 8 ? it + 3 : 7, kB, vB);
    }

    // cross-wave reduction: packed-bf16 partials, one barrier
    unsigned* red_o = (unsigned*)smem;               // [4*64 rows][18]
    float* red_l = (float*)(smem + 18432);
    #pragma unroll
    for (int qs = 0; qs < 4; qs++) {
        int row = qs * 16 + m16;
        unsigned* rw = red_o + (size_t)(wv * 64 + row) * 18;
        *(uint2*)(rw + 2 * quad) =
            make_uint2(pack_bf16_rtz(oacc[qs][0][0], oacc[qs][0][1]),
                       pack_bf16_rtz(oacc[qs][0][2], oacc[qs][0][3]));
        *(uint2*)(rw + 8 + 2 * quad) =
            make_uint2(pack_bf16_rtz(oacc[qs][1][0], oacc[qs][1][1]),
                       pack_bf16_rtz(oacc[qs][1][2], oacc[qs][1][3]));
        if (quad == 0) red_l[wv * 64 + row] = lacc[qs][0];  // rowsum (replicated)
    }
    __syncthreads();

    int q = threadIdx.x >> 2;
    int s4 = (threadIdx.x & 3) * 4;
    float a8[8] = {0.f, 0.f, 0.f, 0.f, 0.f, 0.f, 0.f, 0.f};
    float lt = 0.f;
    #pragma unroll
    for (int w = 0; w < 4; w++) {
        const unsigned* rr = red_o + (size_t)(w * 64 + q) * 18 + s4;
        uint2 ua = *(const uint2*)(rr);
        uint2 ub = *(const uint2*)(rr + 2);
        a8[0] += bf_lo(ua.x); a8[1] += bf_hi(ua.x);
        a8[2] += bf_lo(ua.y); a8[3] += bf_hi(ua.y);
        a8[4] += bf_lo(ub.x); a8[5] += bf_hi(ub.x);
        a8[6] += bf_lo(ub.y); a8[7] += bf_hi(ub.y);
        lt += red_l[w * 64 + q];
    }
    float inv = 1.0f / lt;
    int b = bh >> 2, h = bh & 3;
    int d0 = (threadIdx.x & 3) * 8;
    unsigned short* ob = attnb + ((size_t)b * Lseq + l0 + q) * Cdim + h * HD + d0;
    uint4 u;
    u.x = pack_bf16(a8[0] * inv, a8[1] * inv);
    u.y = pack_bf16(a8[2] * inv, a8[3] * inv);
    u.z = pack_bf16(a8[4] * inv, a8[5] * inv);
    u.w = pack_bf16(a8[6] * inv, a8[7] * inv);
    *(uint4*)ob = u;
}

// ---------------------------------------------------------------------------
// Kernel 3: output projection (w_proj fp32 -> bf16 frags in-reg) + bias +
// residual, fp32 out. Grid 1024: block = 64 o x 32 n.
// ---------------------------------------------------------------------------
__global__ __launch_bounds__(256) void proj_kernel(const float* __restrict__ wp,
        const unsigned short* __restrict__ attnb, const float* __restrict__ bias,
        const float* __restrict__ x, float* __restrict__ out) {
    int bid = blockIdx.x;
    int ot = bid & 1;
    int nt = bid >> 1;                // 0..511, 32-n tiles
    int lane = threadIdx.x & 63;
    int wv = threadIdx.x >> 6;
    int m16 = lane & 15, quad = lane >> 4;
    int o0 = ot * 64 + wv * 16;
    int n0 = nt * 32;

    bf16x8 af[4];
    #pragma unroll
    for (int ks = 0; ks < 4; ks++) {
        const float* p = wp + (size_t)(o0 + m16) * Cdim + ks * 32 + quad * 8;
        float4 f0 = *(const float4*)p;
        float4 f1 = *(const float4*)(p + 4);
        u32x4 u = {pack_bf16(f0.x, f0.y), pack_bf16(f0.z, f0.w),
                   pack_bf16(f1.x, f1.y), pack_bf16(f1.z, f1.w)};
        af[ks] = __builtin_bit_cast(bf16x8, u);
    }
    float bs[4];
    #pragma unroll
    for (int r = 0; r < 4; r++) bs[r] = bias[o0 + quad * 4 + r];
    int oq = o0 + quad * 4;

    #pragma unroll
    for (int lt2 = 0; lt2 < 2; lt2++) {
        int n = n0 + lt2 * 16 + m16;
        f32x4 acc = {0.f, 0.f, 0.f, 0.f};
        #pragma unroll
        for (int ks = 0; ks < 4; ks++) {
            bf16x8 bx = *(const bf16x8*)(attnb + (size_t)n * Cdim + ks * 32 + quad * 8);
            acc = MFMA16(af[ks], bx, acc);
        }
        int b = n >> 11, l = n & (Lseq - 1);
        #pragma unroll
        for (int r = 0; r < 4; r++) {
            size_t xi = ((size_t)b * Cdim + oq + r) * Lseq + l;
            out[xi] = acc[r] + bs[r] + x[xi];
        }
    }
}

extern "C" void kernel_launch(void* const* d_in, const int* in_sizes, int n_in,
                              void* d_out, int out_size, void* d_ws, size_t ws_size,
                              hipStream_t stream) {
    const float* x      = (const float*)d_in[0];
    const float* w_qkv  = (const float*)d_in[1];
    const float* b_qkv  = (const float*)d_in[2];
    const float* w_proj = (const float*)d_in[3];
    const float* b_proj = (const float*)d_in[4];
    float* out = (float*)d_out;

    // ws (ushorts): qh 2M | kh 2M | vh 2M | attnb 2M   (16 MB total)
    const size_t E = (size_t)BH * Lseq * HD;   // 2M elems = 4 MB
    unsigned short* qh    = (unsigned short*)d_ws;
    unsigned short* kh    = qh + E;
    unsigned short* vh    = kh + E;
    unsigned short* attnb = vh + E;

    qkv_kernel<<<dim3(1536), dim3(256), 0, stream>>>(x, w_qkv, b_qkv, qh, kh, vh);
    attn_kernel<<<dim3(BH * 32), dim3(256), 0, stream>>>(qh, kh, vh, attnb);
    proj_kernel<<<dim3(1024), dim3(256), 0, stream>>>(w_proj, attnb, b_proj, x, out);
}